// Round 18
// baseline (116.422 us; speedup 1.0000x reference)
//
#include <hip/hip_runtime.h>
#include <hip/hip_bf16.h>

#define DIM 768
#define NH  12
#define HW  64
#define BB  32
#define NV  100
#define NQ  32
#define NA  32

#define VP_ELEMS (BB * NV * DIM)   // 2457600
#define QP_ELEMS (BB * NQ * DIM)   // 786432
#define AP_ELEMS (BB * NA * DIM)   // 786432
#define S1 (VP_ELEMS)
#define S2 (S1 + QP_ELEMS)
#define STOT (S2 + AP_ELEMS)       // 4030464
#define WELEMS (DIM * DIM)         // 589824
#define NBH (BB * NH)              // 384
#define PREP_BLOCKS (864 + BB)     // 896

typedef __attribute__((ext_vector_type(8))) short     bf16x8;
typedef __attribute__((ext_vector_type(8))) unsigned short u16x8;
typedef __attribute__((ext_vector_type(4))) float     f32x4;

__device__ __forceinline__ float bf16r(float x) {
    return __bfloat162float(__float2bfloat16(x));
}
__device__ __forceinline__ unsigned short f2bu(float x) {
    __hip_bfloat16 h = __float2bfloat16(x);
    return *reinterpret_cast<unsigned short*>(&h);
}
__device__ __forceinline__ float bu2f(unsigned short u) {
    union { unsigned int i; float f; } c;
    c.i = ((unsigned int)u) << 16;
    return c.f;
}

// ---------------------------------------------------------------------------
// PREP (fused): every block zeroes a slice of d_out; blocks 0..863 convert/
// transpose one 64x64 weight tile; blocks 864..895 (one per b) do mask
// compaction (counts, prefix bases, ballot index lists, global row lists).
// ---------------------------------------------------------------------------
__global__ __launch_bounds__(256) void prep(
    const float* __restrict__ W0, const float* __restrict__ W1,
    const float* __restrict__ W2, const float* __restrict__ W3,
    const float* __restrict__ W4, const float* __restrict__ W5,
    unsigned short* __restrict__ WtAll,
    const int* __restrict__ vmask, const int* __restrict__ qmask, const int* __restrict__ amask,
    int* __restrict__ vidx_g, int* __restrict__ qidx_g, int* __restrict__ aidx_g,
    int* __restrict__ vbase_g, int* __restrict__ qbase_g, int* __restrict__ abase_g,
    int* __restrict__ rv_list, int* __restrict__ rq_list, int* __restrict__ ra_list,
    int* __restrict__ tot_g,
    float* __restrict__ out)
{
    const int tid = threadIdx.x;

#pragma unroll
    for (int it = 0; it < 5; ++it) {
        const int e4 = blockIdx.x * 256 + tid + it * (PREP_BLOCKS * 256);
        const int i = e4 * 4;
        if (i < STOT) *(float4*)&out[i] = float4{0.f, 0.f, 0.f, 0.f};
    }

    if (blockIdx.x < 864) {
        __shared__ float tile[64][65];
        const int widx = blockIdx.x / 144;
        const int t    = blockIdx.x % 144;
        const int tr = t / 12, tc = t % 12;
        const float* W = (widx == 0) ? W0 : (widx == 1) ? W1 : (widx == 2) ? W2
                       : (widx == 3) ? W3 : (widx == 4) ? W4 : W5;
        unsigned short* Wt = WtAll + (size_t)widx * WELEMS;
        const int c = tid & 63, r4 = tid >> 6;
#pragma unroll
        for (int it = 0; it < 16; ++it) {
            int r = it * 4 + r4;
            tile[r][c] = W[(size_t)(tr * 64 + r) * DIM + tc * 64 + c];
        }
        __syncthreads();
#pragma unroll
        for (int it = 0; it < 16; ++it) {
            int r = it * 4 + r4;
            Wt[(size_t)(tc * 64 + r) * DIM + tr * 64 + c] = f2bu(tile[c][r]);
        }
        return;
    }

    const int b = blockIdx.x - 864;
    __shared__ int cv[BB], cq[BB], ca[BB];
    __shared__ int bs[3];

    if (tid < BB) {
        int s = 0;
        for (int i = 0; i < NV; ++i) s += (vmask[tid * NV + i] == 0);
        cv[tid] = s;
    } else if (tid >= 64 && tid < 64 + BB) {
        const int bb = tid - 64;
        int s = 0;
        for (int i = 0; i < NQ; ++i) s += (qmask[bb * NQ + i] == 0);
        cq[bb] = s;
    } else if (tid >= 128 && tid < 128 + BB) {
        const int bb = tid - 128;
        int s = 0;
        for (int i = 0; i < NA; ++i) s += (amask[bb * NA + i] == 0);
        ca[bb] = s;
    }
    __syncthreads();

    if (tid == 0) {
        int sv = 0, sq = 0, sa = 0;
        for (int j = 0; j < b; ++j) { sv += cv[j]; sq += cq[j]; sa += ca[j]; }
        bs[0] = sv; bs[1] = sq; bs[2] = sa;
        vbase_g[b] = sv; qbase_g[b] = sq; abase_g[b] = sa;
    }
    if (b == 0 && tid == 1) {
        int sv = 0, sq = 0, sa = 0;
        for (int j = 0; j < BB; ++j) { sv += cv[j]; sq += cq[j]; sa += ca[j]; }
        vbase_g[BB] = sv; qbase_g[BB] = sq; abase_g[BB] = sa;
        tot_g[0] = sv; tot_g[1] = sq; tot_g[2] = sa;
    }
    __syncthreads();
    const int basev = bs[0], baseq = bs[1], basea = bs[2];

    const int lane = tid & 63, w = tid >> 6;
    __shared__ int c0sh;
    const bool mv = (tid < NV) && (vmask[b * NV + tid] == 0);
    const unsigned long long bal = __ballot(mv);
    const int pre = __popcll(bal & ((1ull << lane) - 1ull));
    if (w == 0 && lane == 0) c0sh = __popcll(bal);
    __syncthreads();
    const int vbloc = (w == 0) ? 0 : c0sh;
    if (mv) {
        vidx_g[b * NV + vbloc + pre] = tid;
        rv_list[basev + vbloc + pre] = b * NV + tid;
    }
    const bool mq = (w == 0) && (lane < NQ) && (qmask[b * NQ + lane] == 0);
    const unsigned long long balq = __ballot(mq);
    if (mq) {
        const int preq = __popcll(balq & ((1ull << lane) - 1ull));
        qidx_g[b * NQ + preq] = lane;
        rq_list[baseq + preq] = b * NQ + lane;
    }
    const bool ma = (w == 1) && (lane < NA) && (amask[b * NA + lane] == 0);
    const unsigned long long bala = __ballot(ma);
    if (ma) {
        const int prea = __popcll(bala & ((1ull << lane) - 1ull));
        aidx_g[b * NA + prea] = lane;
        ra_list[basea + prea] = b * NA + lane;
    }
}

// ---------------------------------------------------------------------------
// Row-compacted MFMA out-projection GEMM (validated; OUT=1 path only used).
// 64x128 tile, 4 waves, BK=32. X bf16 dense-compact; f32 out scaled by
// marginal, SCATTERED via rlist (d_out pre-zeroed for masked rows).
// ---------------------------------------------------------------------------
template <int OUT>
__global__ __launch_bounds__(256) void gemm_mfma(
    const void* __restrict__ X0v, const void* __restrict__ X1v, const void* __restrict__ X2v,
    const unsigned short* __restrict__ W0, const unsigned short* __restrict__ W1,
    const unsigned short* __restrict__ W2,
    const float* __restrict__ c0, const float* __restrict__ c1, const float* __restrict__ c2,
    unsigned short* __restrict__ Y0, unsigned short* __restrict__ Y1,
    unsigned short* __restrict__ Y2,
    float* __restrict__ O0, float* __restrict__ O1, float* __restrict__ O2,
    const float* __restrict__ m0, const float* __restrict__ m1, const float* __restrict__ m2,
    const int* __restrict__ rv_list, const int* __restrict__ rq_list, const int* __restrict__ ra_list,
    const int* __restrict__ tot_g)
{
    __shared__ unsigned short As[64 * 32];
    __shared__ unsigned short Bs[128 * 32];

    const int t = blockIdx.x;
    int set, loc;
    if (t < 300)      { set = 0; loc = t; }
    else if (t < 396) { set = 1; loc = t - 300; }
    else              { set = 2; loc = t - 396; }
    const int tm = loc / 6, tn = loc % 6;
    const int cnt = tot_g[set];
    const int bm = tm * 64, bn = tn * 128;
    if (bm >= cnt) return;

    const void* Xv           = (set == 0) ? X0v : (set == 1) ? X1v : X2v;
    const unsigned short* Wt = (set == 0) ? W0 : (set == 1) ? W1 : W2;
    const float* bias        = (set == 0) ? c0 : (set == 1) ? c1 : c2;
    unsigned short* Y        = (set == 0) ? Y0 : (set == 1) ? Y1 : Y2;
    float* Out               = (set == 0) ? O0 : (set == 1) ? O1 : O2;
    const float* mg          = (set == 0) ? m0 : (set == 1) ? m1 : m2;
    const int* rlist         = (set == 0) ? rv_list : (set == 1) ? rq_list : ra_list;
    const int S              = (set == 0) ? NV : NQ;

    const int tid = threadIdx.x, lane = tid & 63, wave = tid >> 6;
    const int col = lane & 15, rg = lane >> 4;

    const int arow = tid >> 2, akc = (tid & 3) << 3;
    const int brow = tid >> 1, bkc = (tid & 1) << 4;
    const int grow = bm + arow;
    const int asrc = (OUT == 0 && grow < cnt) ? rlist[grow] : 0;

    f32x4 acc[4][2] = {};

    for (int k0 = 0; k0 < DIM; k0 += 32) {
        if (OUT == 0) {
            u16x8 u = {};
            if (grow < cnt) {
                const float* Xf = (const float*)Xv;
                const float4 f0 = *(const float4*)&Xf[(size_t)asrc * DIM + k0 + akc];
                const float4 f1 = *(const float4*)&Xf[(size_t)asrc * DIM + k0 + akc + 4];
                u[0] = f2bu(f0.x); u[1] = f2bu(f0.y); u[2] = f2bu(f0.z); u[3] = f2bu(f0.w);
                u[4] = f2bu(f1.x); u[5] = f2bu(f1.y); u[6] = f2bu(f1.z); u[7] = f2bu(f1.w);
            }
            *(u16x8*)&As[arow * 32 + akc] = u;
        } else {
            const unsigned short* Xb = (const unsigned short*)Xv;
            *(u16x8*)&As[arow * 32 + akc] =
                *(const u16x8*)&Xb[(size_t)grow * DIM + k0 + akc];
        }
        *(u16x8*)&Bs[brow * 32 + bkc] =
            *(const u16x8*)&Wt[(size_t)(bn + brow) * DIM + k0 + bkc];
        *(u16x8*)&Bs[brow * 32 + bkc + 8] =
            *(const u16x8*)&Wt[(size_t)(bn + brow) * DIM + k0 + bkc + 8];
        __syncthreads();

        bf16x8 af[4], bfr[2];
#pragma unroll
        for (int mi = 0; mi < 4; ++mi)
            af[mi] = *(const bf16x8*)&As[(mi * 16 + col) * 32 + rg * 8];
#pragma unroll
        for (int ni = 0; ni < 2; ++ni)
            bfr[ni] = *(const bf16x8*)&Bs[(wave * 32 + ni * 16 + col) * 32 + rg * 8];
#pragma unroll
        for (int mi = 0; mi < 4; ++mi)
#pragma unroll
            for (int ni = 0; ni < 2; ++ni)
                acc[mi][ni] = __builtin_amdgcn_mfma_f32_16x16x32_bf16(
                    af[mi], bfr[ni], acc[mi][ni], 0, 0, 0);
        __syncthreads();
    }

    const int h = (bn + wave * 32) >> 6;
#pragma unroll
    for (int mi = 0; mi < 4; ++mi) {
#pragma unroll
        for (int r = 0; r < 4; ++r) {
            const int m = bm + mi * 16 + rg * 4 + r;
            if (m >= cnt) continue;
            if (!OUT) {
#pragma unroll
                for (int ni = 0; ni < 2; ++ni) {
                    const int n = bn + wave * 32 + ni * 16 + col;
                    Y[(size_t)m * DIM + n] = f2bu(acc[mi][ni][r] + bias[n]);
                }
            } else {
                const int src = rlist[m];
                const int bb = src / S, ss = src - bb * S;
                const float mgv = mg[(bb * NH + h) * S + ss];
#pragma unroll
                for (int ni = 0; ni < 2; ++ni) {
                    const int n = bn + wave * 32 + ni * 16 + col;
                    Out[(size_t)src * DIM + n] = bf16r((acc[mi][ni][r] + bias[n]) * mgv);
                }
            }
        }
    }
}

// ---------------------------------------------------------------------------
// MFMA marginal kernel v7 — PROJECTION FUSED IN. One block per (b,h).
// Phase A: block computes the h-th 64-col slice of the v/q/a projections
// for its b's compact rows (16-row MFMA tiles, A gathered f32->bf16 from
// global via rlist, B = Wt rows direct; same MFMA order as the old gemm<0>
// -> bitwise-identical projections), writes them to LDS AND to vpb/qpb/apb
// (12 h-slices x 32 b jointly cover the full tensors for gemm<1>).
// Phase B/C: validated v6 score + reduce + normalize + scatter.
// ---------------------------------------------------------------------------
__global__ __launch_bounds__(256, 2) void marginal_proj(
    const float* __restrict__ v, const float* __restrict__ q, const float* __restrict__ a,
    const unsigned short* __restrict__ WtAll,
    const float* __restrict__ bv, const float* __restrict__ bq, const float* __restrict__ ba,
    const int* __restrict__ vbase_g, const int* __restrict__ qbase_g, const int* __restrict__ abase_g,
    const int* __restrict__ vidx_g, const int* __restrict__ qidx_g, const int* __restrict__ aidx_g,
    const int* __restrict__ rv_list, const int* __restrict__ rq_list, const int* __restrict__ ra_list,
    unsigned short* __restrict__ vpb, unsigned short* __restrict__ qpb, unsigned short* __restrict__ apb,
    float* __restrict__ pv, float* __restrict__ pq, float* __restrict__ pa)
{
    const int bh = blockIdx.x;
    const int b = bh / NH, h = bh % NH;
    const int tid = threadIdx.x, lane = tid & 63, wave = tid >> 6;
    const int col = lane & 15, rg = lane >> 4;

    __shared__ unsigned short vhs[112 * 72];
    __shared__ unsigned short qhs[NQ * 72];
    __shared__ unsigned short ahs[NA * 72];
    __shared__ float aoff[NA];
    __shared__ float pv_sh[112], pa_sh[NA], pq_sh[NQ];
    __shared__ float zsh;

    const int vb0 = vbase_g[b], vcnt = vbase_g[b + 1] - vb0;
    const int qb0 = qbase_g[b], qcnt = qbase_g[b + 1] - qb0;
    const int ab0 = abase_g[b], acnt = abase_g[b + 1] - ab0;

    if (tid < 112) pv_sh[tid] = 0.f;
    if (tid < NA)  { aoff[tid] = (tid < acnt) ? 0.f : -200.f; pa_sh[tid] = 0.f; }

    const int nvt = (vcnt + 15) >> 4;
    const int nqt = (qcnt + 15) >> 4;
    const int nat = (acnt + 15) >> 4;
    const int T = nvt + nqt + nat;

    // ---- Phase A: projection slices (M=16 tiles, N=64, K=768) ----
    for (int t = wave; t < T; t += 4) {
        int m0, rbase, ccnt;
        const float* Xf; const float* biasp; const int* rlist;
        unsigned short* Xpb; unsigned short* ldst; const unsigned short* Wt;
        if (t < nvt) {
            m0 = t * 16; rbase = vb0; ccnt = vcnt; Xf = v; biasp = bv;
            rlist = rv_list; Xpb = vpb; ldst = vhs; Wt = WtAll;
        } else if (t < nvt + nqt) {
            m0 = (t - nvt) * 16; rbase = qb0; ccnt = qcnt; Xf = q; biasp = bq;
            rlist = rq_list; Xpb = qpb; ldst = qhs; Wt = WtAll + WELEMS;
        } else {
            m0 = (t - nvt - nqt) * 16; rbase = ab0; ccnt = acnt; Xf = a; biasp = ba;
            rlist = ra_list; Xpb = apb; ldst = ahs; Wt = WtAll + 2 * WELEMS;
        }
        const int lrow = m0 + col;
        const int crow = (lrow < ccnt) ? lrow : (ccnt - 1);
        const int srow = rlist[rbase + crow];
        const int kc = rg * 8;
        f32x4 pacc[4] = {};
        for (int k0 = 0; k0 < DIM; k0 += 32) {
            const float4 f0 = *(const float4*)&Xf[(size_t)srow * DIM + k0 + kc];
            const float4 f1 = *(const float4*)&Xf[(size_t)srow * DIM + k0 + kc + 4];
            bf16x8 af;
            af[0] = (short)f2bu(f0.x); af[1] = (short)f2bu(f0.y);
            af[2] = (short)f2bu(f0.z); af[3] = (short)f2bu(f0.w);
            af[4] = (short)f2bu(f1.x); af[5] = (short)f2bu(f1.y);
            af[6] = (short)f2bu(f1.z); af[7] = (short)f2bu(f1.w);
#pragma unroll
            for (int ni = 0; ni < 4; ++ni) {
                const bf16x8 bfr = *(const bf16x8*)&Wt[(size_t)(h * 64 + ni * 16 + col) * DIM + k0 + kc];
                pacc[ni] = __builtin_amdgcn_mfma_f32_16x16x32_bf16(af, bfr, pacc[ni], 0, 0, 0);
            }
        }
        // C layout: ncol = lane&15, mrow = rg*4 + r (validated)
#pragma unroll
        for (int ni = 0; ni < 4; ++ni) {
#pragma unroll
            for (int r = 0; r < 4; ++r) {
                const int m = m0 + rg * 4 + r;
                const int lc = ni * 16 + col;
                const unsigned short u = f2bu(pacc[ni][r] + biasp[h * 64 + lc]);
                ldst[m * 72 + lc] = u;
                if (m < ccnt) Xpb[(size_t)(rbase + m) * DIM + h * 64 + lc] = u;
            }
        }
    }
    __syncthreads();

    // ---- Phase B: scores + marginals (validated v6 inner loop) ----
    float pvacc[7][4] = {};
    float za0 = 0.f, za1 = 0.f;
    const float sc2 = 0.125f * 1.44269504088896f;   // scale * log2(e)

    for (int qs = wave; qs < qcnt; qs += 4) {
        float zq = 0.f;
#pragma unroll
        for (int ah = 0; ah < 2; ++ah) {
            if (ah < nat) {
                const int ai = (ah << 4) + col;
                const u16x8 qv0 = *(const u16x8*)&qhs[qs * 72 + rg * 8];
                const u16x8 qv1 = *(const u16x8*)&qhs[qs * 72 + 32 + rg * 8];
                const u16x8 av0 = *(const u16x8*)&ahs[ai * 72 + rg * 8];
                const u16x8 av1 = *(const u16x8*)&ahs[ai * 72 + 32 + rg * 8];
                bf16x8 bf0, bf1;
#pragma unroll
                for (int j = 0; j < 8; ++j) {
                    bf0[j] = (short)f2bu(bu2f(qv0[j]) * bu2f(av0[j]));
                    bf1[j] = (short)f2bu(bu2f(qv1[j]) * bu2f(av1[j]));
                }
                const float poff = aoff[ai];
                float ts = 0.f;
#pragma unroll
                for (int vt = 0; vt < 7; ++vt) {
                    if (vt < nvt) {
                        const bf16x8 a0 = *(const bf16x8*)&vhs[(vt * 16 + col) * 72 + rg * 8];
                        const bf16x8 a1 = *(const bf16x8*)&vhs[(vt * 16 + col) * 72 + 32 + rg * 8];
                        f32x4 acc = {};
                        acc = __builtin_amdgcn_mfma_f32_16x16x32_bf16(a0, bf0, acc, 0, 0, 0);
                        acc = __builtin_amdgcn_mfma_f32_16x16x32_bf16(a1, bf1, acc, 0, 0, 0);
                        if ((vt + 1) * 16 <= vcnt) {
#pragma unroll
                            for (int r = 0; r < 4; ++r) {
                                const float e = exp2f(fmaf(acc[r], sc2, poff));
                                pvacc[vt][r] += e;
                                ts += e;
                            }
                        } else {
#pragma unroll
                            for (int r = 0; r < 4; ++r) {
                                const float off = (vt * 16 + rg * 4 + r < vcnt) ? poff : -200.f;
                                const float e = exp2f(fmaf(acc[r], sc2, off));
                                pvacc[vt][r] += e;
                                ts += e;
                            }
                        }
                    }
                }
                if (ah) za1 += ts; else za0 += ts;
                zq += ts;
            }
        }
        zq += __shfl_xor(zq, 1);  zq += __shfl_xor(zq, 2);  zq += __shfl_xor(zq, 4);
        zq += __shfl_xor(zq, 8);  zq += __shfl_xor(zq, 16); zq += __shfl_xor(zq, 32);
        if (lane == 0) pq_sh[qs] = zq;
    }

    // ---- Phase C: cross-wave reduce + normalize + scatter (validated) ----
#pragma unroll
    for (int vt = 0; vt < 7; ++vt) {
        if (vt < nvt) {
#pragma unroll
            for (int r = 0; r < 4; ++r) {
                float x = pvacc[vt][r];
                x += __shfl_xor(x, 1); x += __shfl_xor(x, 2);
                x += __shfl_xor(x, 4); x += __shfl_xor(x, 8);
                if (col == 0) atomicAdd(&pv_sh[vt * 16 + rg * 4 + r], x);
            }
        }
    }
    {
        float x = za0;
        x += __shfl_xor(x, 16); x += __shfl_xor(x, 32);
        if (rg == 0) atomicAdd(&pa_sh[col], x);
        float y = za1;
        y += __shfl_xor(y, 16); y += __shfl_xor(y, 32);
        if (rg == 0) atomicAdd(&pa_sh[16 + col], y);
    }
    __syncthreads();

    if (tid < 64) {
        float x = (lane < qcnt) ? pq_sh[lane] : 0.f;
        x += __shfl_xor(x, 1); x += __shfl_xor(x, 2); x += __shfl_xor(x, 4);
        x += __shfl_xor(x, 8); x += __shfl_xor(x, 16); x += __shfl_xor(x, 32);
        if (lane == 0) zsh = x;
    }
    if (tid < NV) pv[bh * NV + tid] = 0.f;
    if (tid < NQ) pq[bh * NQ + tid] = 0.f;
    if (tid < NA) pa[bh * NA + tid] = 0.f;
    __syncthreads();
    const float invZ = 1.0f / zsh;
    if (tid < vcnt) pv[bh * NV + vidx_g[b * NV + tid]] = pv_sh[tid] * invZ;
    if (tid < qcnt) pq[bh * NQ + qidx_g[b * NQ + tid]] = pq_sh[tid] * invZ;
    if (tid < acnt) pa[bh * NA + aidx_g[b * NA + tid]] = pa_sh[tid] * invZ;
}

// ---------------------------------------------------------------------------
extern "C" void kernel_launch(void* const* d_in, const int* in_sizes, int n_in,
                              void* d_out, int out_size, void* d_ws, size_t ws_size,
                              hipStream_t stream)
{
    const float* v     = (const float*)d_in[0];
    const float* q     = (const float*)d_in[1];
    const float* a     = (const float*)d_in[2];
    const int*   vmask = (const int*)d_in[3];
    const int*   qmask = (const int*)d_in[4];
    const int*   amask = (const int*)d_in[5];
    const float* Wv  = (const float*)d_in[6];
    const float* bv  = (const float*)d_in[7];
    const float* Wq  = (const float*)d_in[8];
    const float* bq  = (const float*)d_in[9];
    const float* Wa  = (const float*)d_in[10];
    const float* ba  = (const float*)d_in[11];
    const float* Wvo = (const float*)d_in[12];
    const float* bvo = (const float*)d_in[13];
    const float* Wqo = (const float*)d_in[14];
    const float* bqo = (const float*)d_in[15];
    const float* Wao = (const float*)d_in[16];
    const float* bao = (const float*)d_in[17];
    float* out = (float*)d_out;          // reference output dtype is FLOAT32

    unsigned short* wsu = (unsigned short*)d_ws;
    unsigned short* WtAll = wsu;                    // 6 * 589824
    unsigned short* vpb   = WtAll + 6 * WELEMS;     // up to 2457600 (compact)
    unsigned short* qpb   = vpb + VP_ELEMS;         // up to 786432
    unsigned short* apb   = qpb + QP_ELEMS;         // up to 786432
    float* fbase   = (float*)(apb + AP_ELEMS);
    float* pv      = fbase;                         // 384*100
    float* pq      = pv + NBH * NV;                 // 384*32
    float* pa      = pq + NBH * NQ;                 // 384*32
    int* vidx_g    = (int*)(pa + NBH * NA);         // 32*100
    int* qidx_g    = vidx_g + BB * NV;              // 32*32
    int* aidx_g    = qidx_g + BB * NQ;              // 32*32
    int* vbase_g   = aidx_g + BB * NA;              // 33
    int* qbase_g   = vbase_g + BB + 1;              // 33
    int* abase_g   = qbase_g + BB + 1;              // 33
    int* rv_list   = abase_g + BB + 1;              // 3200
    int* rq_list   = rv_list + BB * NV;             // 1024
    int* ra_list   = rq_list + BB * NQ;             // 1024
    int* tot_g     = ra_list + BB * NA;             // 3

    prep<<<dim3(PREP_BLOCKS), dim3(256), 0, stream>>>(
        Wv, Wq, Wa, Wvo, Wqo, Wao, WtAll,
        vmask, qmask, amask,
        vidx_g, qidx_g, aidx_g, vbase_g, qbase_g, abase_g,
        rv_list, rq_list, ra_list, tot_g, out);

    marginal_proj<<<dim3(NBH), dim3(256), 0, stream>>>(
        v, q, a, WtAll, bv, bq, ba,
        vbase_g, qbase_g, abase_g,
        vidx_g, qidx_g, aidx_g,
        rv_list, rq_list, ra_list,
        vpb, qpb, apb, pv, pq, pa);

    gemm_mfma<1><<<dim3(492), dim3(256), 0, stream>>>(
        vpb, qpb, apb,
        WtAll + 3 * WELEMS, WtAll + 4 * WELEMS, WtAll + 5 * WELEMS,
        bvo, bqo, bao,
        nullptr, nullptr, nullptr,
        out, out + S1, out + S2,
        pv, pq, pa,
        rv_list, rq_list, ra_list, tot_g);
}

// Round 19
// 85.220 us; speedup vs baseline: 1.3661x; 1.3661x over previous
//
#include <hip/hip_runtime.h>
#include <hip/hip_bf16.h>

#define DIM 768
#define NH  12
#define HW  64
#define BB  32
#define NV  100
#define NQ  32
#define NA  32

#define VP_ELEMS (BB * NV * DIM)   // 2457600
#define QP_ELEMS (BB * NQ * DIM)   // 786432
#define AP_ELEMS (BB * NA * DIM)   // 786432
#define S1 (VP_ELEMS)
#define S2 (S1 + QP_ELEMS)
#define STOT (S2 + AP_ELEMS)       // 4030464
#define WELEMS (DIM * DIM)         // 589824
#define NBH (BB * NH)              // 384
#define PREP_BLOCKS (864 + BB)     // 896

typedef __attribute__((ext_vector_type(8))) short     bf16x8;
typedef __attribute__((ext_vector_type(8))) unsigned short u16x8;
typedef __attribute__((ext_vector_type(4))) float     f32x4;

__device__ __forceinline__ float bf16r(float x) {
    return __bfloat162float(__float2bfloat16(x));
}
__device__ __forceinline__ unsigned short f2bu(float x) {
    __hip_bfloat16 h = __float2bfloat16(x);
    return *reinterpret_cast<unsigned short*>(&h);
}
__device__ __forceinline__ float bu2f(unsigned short u) {
    union { unsigned int i; float f; } c;
    c.i = ((unsigned int)u) << 16;
    return c.f;
}

// ---------------------------------------------------------------------------
// PREP (fused): every block zeroes a slice of d_out; blocks 0..863 convert/
// transpose one 64x64 weight tile; blocks 864..895 (one per b) do mask
// compaction (counts, prefix bases, ballot index lists, global row lists).
// ---------------------------------------------------------------------------
__global__ __launch_bounds__(256) void prep(
    const float* __restrict__ W0, const float* __restrict__ W1,
    const float* __restrict__ W2, const float* __restrict__ W3,
    const float* __restrict__ W4, const float* __restrict__ W5,
    unsigned short* __restrict__ WtAll,
    const int* __restrict__ vmask, const int* __restrict__ qmask, const int* __restrict__ amask,
    int* __restrict__ vidx_g, int* __restrict__ qidx_g, int* __restrict__ aidx_g,
    int* __restrict__ vbase_g, int* __restrict__ qbase_g, int* __restrict__ abase_g,
    int* __restrict__ rv_list, int* __restrict__ rq_list, int* __restrict__ ra_list,
    int* __restrict__ tot_g,
    float* __restrict__ out)
{
    const int tid = threadIdx.x;

#pragma unroll
    for (int it = 0; it < 5; ++it) {
        const int e4 = blockIdx.x * 256 + tid + it * (PREP_BLOCKS * 256);
        const int i = e4 * 4;
        if (i < STOT) *(float4*)&out[i] = float4{0.f, 0.f, 0.f, 0.f};
    }

    if (blockIdx.x < 864) {
        __shared__ float tile[64][65];
        const int widx = blockIdx.x / 144;
        const int t    = blockIdx.x % 144;
        const int tr = t / 12, tc = t % 12;
        const float* W = (widx == 0) ? W0 : (widx == 1) ? W1 : (widx == 2) ? W2
                       : (widx == 3) ? W3 : (widx == 4) ? W4 : W5;
        unsigned short* Wt = WtAll + (size_t)widx * WELEMS;
        const int c = tid & 63, r4 = tid >> 6;
#pragma unroll
        for (int it = 0; it < 16; ++it) {
            int r = it * 4 + r4;
            tile[r][c] = W[(size_t)(tr * 64 + r) * DIM + tc * 64 + c];
        }
        __syncthreads();
#pragma unroll
        for (int it = 0; it < 16; ++it) {
            int r = it * 4 + r4;
            Wt[(size_t)(tc * 64 + r) * DIM + tr * 64 + c] = f2bu(tile[c][r]);
        }
        return;
    }

    const int b = blockIdx.x - 864;
    __shared__ int cv[BB], cq[BB], ca[BB];
    __shared__ int bs[3];

    if (tid < BB) {
        int s = 0;
        for (int i = 0; i < NV; ++i) s += (vmask[tid * NV + i] == 0);
        cv[tid] = s;
    } else if (tid >= 64 && tid < 64 + BB) {
        const int bb = tid - 64;
        int s = 0;
        for (int i = 0; i < NQ; ++i) s += (qmask[bb * NQ + i] == 0);
        cq[bb] = s;
    } else if (tid >= 128 && tid < 128 + BB) {
        const int bb = tid - 128;
        int s = 0;
        for (int i = 0; i < NA; ++i) s += (amask[bb * NA + i] == 0);
        ca[bb] = s;
    }
    __syncthreads();

    if (tid == 0) {
        int sv = 0, sq = 0, sa = 0;
        for (int j = 0; j < b; ++j) { sv += cv[j]; sq += cq[j]; sa += ca[j]; }
        bs[0] = sv; bs[1] = sq; bs[2] = sa;
        vbase_g[b] = sv; qbase_g[b] = sq; abase_g[b] = sa;
    }
    if (b == 0 && tid == 1) {
        int sv = 0, sq = 0, sa = 0;
        for (int j = 0; j < BB; ++j) { sv += cv[j]; sq += cq[j]; sa += ca[j]; }
        vbase_g[BB] = sv; qbase_g[BB] = sq; abase_g[BB] = sa;
        tot_g[0] = sv; tot_g[1] = sq; tot_g[2] = sa;
    }
    __syncthreads();
    const int basev = bs[0], baseq = bs[1], basea = bs[2];

    const int lane = tid & 63, w = tid >> 6;
    __shared__ int c0sh;
    const bool mv = (tid < NV) && (vmask[b * NV + tid] == 0);
    const unsigned long long bal = __ballot(mv);
    const int pre = __popcll(bal & ((1ull << lane) - 1ull));
    if (w == 0 && lane == 0) c0sh = __popcll(bal);
    __syncthreads();
    const int vbloc = (w == 0) ? 0 : c0sh;
    if (mv) {
        vidx_g[b * NV + vbloc + pre] = tid;
        rv_list[basev + vbloc + pre] = b * NV + tid;
    }
    const bool mq = (w == 0) && (lane < NQ) && (qmask[b * NQ + lane] == 0);
    const unsigned long long balq = __ballot(mq);
    if (mq) {
        const int preq = __popcll(balq & ((1ull << lane) - 1ull));
        qidx_g[b * NQ + preq] = lane;
        rq_list[baseq + preq] = b * NQ + lane;
    }
    const bool ma = (w == 1) && (lane < NA) && (amask[b * NA + lane] == 0);
    const unsigned long long bala = __ballot(ma);
    if (ma) {
        const int prea = __popcll(bala & ((1ull << lane) - 1ull));
        aidx_g[b * NA + prea] = lane;
        ra_list[basea + prea] = b * NA + lane;
    }
}

// ---------------------------------------------------------------------------
// Row-compacted MFMA GEMM, 3 sets. 64x128 tile, 4 waves, BK=32. (validated)
// OUT=0: X f32, rows GATHERED via rlist (compact -> dense Y bf16).
// OUT=1: X bf16 dense-compact; f32 out scaled by marginal, SCATTERED via
//        rlist to original rows (d_out pre-zeroed for masked rows).
// ---------------------------------------------------------------------------
template <int OUT>
__global__ __launch_bounds__(256) void gemm_mfma(
    const void* __restrict__ X0v, const void* __restrict__ X1v, const void* __restrict__ X2v,
    const unsigned short* __restrict__ W0, const unsigned short* __restrict__ W1,
    const unsigned short* __restrict__ W2,
    const float* __restrict__ c0, const float* __restrict__ c1, const float* __restrict__ c2,
    unsigned short* __restrict__ Y0, unsigned short* __restrict__ Y1,
    unsigned short* __restrict__ Y2,
    float* __restrict__ O0, float* __restrict__ O1, float* __restrict__ O2,
    const float* __restrict__ m0, const float* __restrict__ m1, const float* __restrict__ m2,
    const int* __restrict__ rv_list, const int* __restrict__ rq_list, const int* __restrict__ ra_list,
    const int* __restrict__ tot_g)
{
    __shared__ unsigned short As[64 * 32];
    __shared__ unsigned short Bs[128 * 32];

    const int t = blockIdx.x;
    int set, loc;
    if (t < 300)      { set = 0; loc = t; }
    else if (t < 396) { set = 1; loc = t - 300; }
    else              { set = 2; loc = t - 396; }
    const int tm = loc / 6, tn = loc % 6;
    const int cnt = tot_g[set];
    const int bm = tm * 64, bn = tn * 128;
    if (bm >= cnt) return;

    const void* Xv           = (set == 0) ? X0v : (set == 1) ? X1v : X2v;
    const unsigned short* Wt = (set == 0) ? W0 : (set == 1) ? W1 : W2;
    const float* bias        = (set == 0) ? c0 : (set == 1) ? c1 : c2;
    unsigned short* Y        = (set == 0) ? Y0 : (set == 1) ? Y1 : Y2;
    float* Out               = (set == 0) ? O0 : (set == 1) ? O1 : O2;
    const float* mg          = (set == 0) ? m0 : (set == 1) ? m1 : m2;
    const int* rlist         = (set == 0) ? rv_list : (set == 1) ? rq_list : ra_list;
    const int S              = (set == 0) ? NV : NQ;

    const int tid = threadIdx.x, lane = tid & 63, wave = tid >> 6;
    const int col = lane & 15, rg = lane >> 4;

    const int arow = tid >> 2, akc = (tid & 3) << 3;
    const int brow = tid >> 1, bkc = (tid & 1) << 4;
    const int grow = bm + arow;
    const int asrc = (OUT == 0 && grow < cnt) ? rlist[grow] : 0;

    f32x4 acc[4][2] = {};

    for (int k0 = 0; k0 < DIM; k0 += 32) {
        if (OUT == 0) {
            u16x8 u = {};
            if (grow < cnt) {
                const float* Xf = (const float*)Xv;
                const float4 f0 = *(const float4*)&Xf[(size_t)asrc * DIM + k0 + akc];
                const float4 f1 = *(const float4*)&Xf[(size_t)asrc * DIM + k0 + akc + 4];
                u[0] = f2bu(f0.x); u[1] = f2bu(f0.y); u[2] = f2bu(f0.z); u[3] = f2bu(f0.w);
                u[4] = f2bu(f1.x); u[5] = f2bu(f1.y); u[6] = f2bu(f1.z); u[7] = f2bu(f1.w);
            }
            *(u16x8*)&As[arow * 32 + akc] = u;
        } else {
            const unsigned short* Xb = (const unsigned short*)Xv;
            *(u16x8*)&As[arow * 32 + akc] =
                *(const u16x8*)&Xb[(size_t)grow * DIM + k0 + akc];
        }
        *(u16x8*)&Bs[brow * 32 + bkc] =
            *(const u16x8*)&Wt[(size_t)(bn + brow) * DIM + k0 + bkc];
        *(u16x8*)&Bs[brow * 32 + bkc + 8] =
            *(const u16x8*)&Wt[(size_t)(bn + brow) * DIM + k0 + bkc + 8];
        __syncthreads();

        bf16x8 af[4], bfr[2];
#pragma unroll
        for (int mi = 0; mi < 4; ++mi)
            af[mi] = *(const bf16x8*)&As[(mi * 16 + col) * 32 + rg * 8];
#pragma unroll
        for (int ni = 0; ni < 2; ++ni)
            bfr[ni] = *(const bf16x8*)&Bs[(wave * 32 + ni * 16 + col) * 32 + rg * 8];
#pragma unroll
        for (int mi = 0; mi < 4; ++mi)
#pragma unroll
            for (int ni = 0; ni < 2; ++ni)
                acc[mi][ni] = __builtin_amdgcn_mfma_f32_16x16x32_bf16(
                    af[mi], bfr[ni], acc[mi][ni], 0, 0, 0);
        __syncthreads();
    }

    // C layout (validated): n-col = lane&15, m-row = (lane>>4)*4 + r
    const int h = (bn + wave * 32) >> 6;   // uniform per wave
#pragma unroll
    for (int mi = 0; mi < 4; ++mi) {
#pragma unroll
        for (int r = 0; r < 4; ++r) {
            const int m = bm + mi * 16 + rg * 4 + r;
            if (m >= cnt) continue;
            if (!OUT) {
#pragma unroll
                for (int ni = 0; ni < 2; ++ni) {
                    const int n = bn + wave * 32 + ni * 16 + col;
                    Y[(size_t)m * DIM + n] = f2bu(acc[mi][ni][r] + bias[n]);
                }
            } else {
                const int src = rlist[m];
                const int bb = src / S, ss = src - bb * S;
                const float mgv = mg[(bb * NH + h) * S + ss];
#pragma unroll
                for (int ni = 0; ni < 2; ++ni) {
                    const int n = bn + wave * 32 + ni * 16 + col;
                    Out[(size_t)src * DIM + n] = bf16r((acc[mi][ni][r] + bias[n]) * mgv);
                }
            }
        }
    }
}

// ---------------------------------------------------------------------------
// MFMA marginal kernel v6 — fully compacted, ONE block per bh, with the
// normalize + scatter fused in-block. Inner loop identical to validated v5.
// ---------------------------------------------------------------------------
__global__ __launch_bounds__(256, 2) void marginal_norm(
    const unsigned short* __restrict__ vp, const unsigned short* __restrict__ qp,
    const unsigned short* __restrict__ ap,
    const int* __restrict__ vbase_g, const int* __restrict__ qbase_g, const int* __restrict__ abase_g,
    const int* __restrict__ vidx_g, const int* __restrict__ qidx_g, const int* __restrict__ aidx_g,
    float* __restrict__ pv, float* __restrict__ pq, float* __restrict__ pa)
{
    const int bh = blockIdx.x;
    const int b = bh / NH, h = bh % NH;
    const int tid = threadIdx.x, lane = tid & 63, wave = tid >> 6;
    const int col = lane & 15, rg = lane >> 4;

    __shared__ unsigned short vhs[112 * 72];
    __shared__ unsigned short qhs[NQ * 72];
    __shared__ unsigned short ahs[NA * 72];
    __shared__ float aoff[NA];
    __shared__ float pv_sh[112], pa_sh[NA], pq_sh[NQ];
    __shared__ float zsh;

    const int vb0 = vbase_g[b], vcnt = vbase_g[b + 1] - vb0;
    const int qb0 = qbase_g[b], qcnt = qbase_g[b + 1] - qb0;
    const int ab0 = abase_g[b], acnt = abase_g[b + 1] - ab0;

    if (tid < 112) pv_sh[tid] = 0.f;
    if (tid < NA)  { aoff[tid] = (tid < acnt) ? 0.f : -200.f; pa_sh[tid] = 0.f; }

    for (int i = tid >> 3; i < vcnt; i += 32) {
        const int c = tid & 7;
        *(u16x8*)&vhs[i * 72 + c * 8] =
            *(const u16x8*)&vp[(size_t)(vb0 + i) * DIM + h * 64 + c * 8];
    }
    {   // zero v pad rows up to next multiple of 16
        const int pr = vcnt + (tid >> 3);
        if ((tid >> 3) < 16 && pr < 112) {
            const int c = tid & 7;
            u16x8 z = {};
            *(u16x8*)&vhs[pr * 72 + c * 8] = z;
        }
    }
    for (int i = tid >> 3; i < qcnt; i += 32) {
        const int c = tid & 7;
        *(u16x8*)&qhs[i * 72 + c * 8] =
            *(const u16x8*)&qp[(size_t)(qb0 + i) * DIM + h * 64 + c * 8];
    }
    for (int i = tid >> 3; i < acnt; i += 32) {
        const int c = tid & 7;
        *(u16x8*)&ahs[i * 72 + c * 8] =
            *(const u16x8*)&ap[(size_t)(ab0 + i) * DIM + h * 64 + c * 8];
    }
    {   // zero a pad rows
        const int pr = acnt + (tid >> 3);
        if ((tid >> 3) < 16 && pr < NA) {
            const int c = tid & 7;
            u16x8 z = {};
            *(u16x8*)&ahs[pr * 72 + c * 8] = z;
        }
    }
    __syncthreads();

    const int nvt = (vcnt + 15) >> 4;
    const int nat = (acnt + 15) >> 4;

    float pvacc[7][4] = {};
    float za0 = 0.f, za1 = 0.f;
    const float sc2 = 0.125f * 1.44269504088896f;   // scale * log2(e)

    for (int qs = wave; qs < qcnt; qs += 4) {
        float zq = 0.f;
#pragma unroll
        for (int ah = 0; ah < 2; ++ah) {
            if (ah < nat) {
                const int ai = (ah << 4) + col;
                const u16x8 qv0 = *(const u16x8*)&qhs[qs * 72 + rg * 8];
                const u16x8 qv1 = *(const u16x8*)&qhs[qs * 72 + 32 + rg * 8];
                const u16x8 av0 = *(const u16x8*)&ahs[ai * 72 + rg * 8];
                const u16x8 av1 = *(const u16x8*)&ahs[ai * 72 + 32 + rg * 8];
                bf16x8 bf0, bf1;
#pragma unroll
                for (int j = 0; j < 8; ++j) {
                    bf0[j] = (short)f2bu(bu2f(qv0[j]) * bu2f(av0[j]));
                    bf1[j] = (short)f2bu(bu2f(qv1[j]) * bu2f(av1[j]));
                }
                const float poff = aoff[ai];
                float ts = 0.f;
#pragma unroll
                for (int vt = 0; vt < 7; ++vt) {
                    if (vt < nvt) {
                        const bf16x8 a0 = *(const bf16x8*)&vhs[(vt * 16 + col) * 72 + rg * 8];
                        const bf16x8 a1 = *(const bf16x8*)&vhs[(vt * 16 + col) * 72 + 32 + rg * 8];
                        f32x4 acc = {};
                        acc = __builtin_amdgcn_mfma_f32_16x16x32_bf16(a0, bf0, acc, 0, 0, 0);
                        acc = __builtin_amdgcn_mfma_f32_16x16x32_bf16(a1, bf1, acc, 0, 0, 0);
                        if ((vt + 1) * 16 <= vcnt) {
#pragma unroll
                            for (int r = 0; r < 4; ++r) {
                                const float e = exp2f(fmaf(acc[r], sc2, poff));
                                pvacc[vt][r] += e;
                                ts += e;
                            }
                        } else {
#pragma unroll
                            for (int r = 0; r < 4; ++r) {
                                const float off = (vt * 16 + rg * 4 + r < vcnt) ? poff : -200.f;
                                const float e = exp2f(fmaf(acc[r], sc2, off));
                                pvacc[vt][r] += e;
                                ts += e;
                            }
                        }
                    }
                }
                if (ah) za1 += ts; else za0 += ts;
                zq += ts;
            }
        }
        zq += __shfl_xor(zq, 1);  zq += __shfl_xor(zq, 2);  zq += __shfl_xor(zq, 4);
        zq += __shfl_xor(zq, 8);  zq += __shfl_xor(zq, 16); zq += __shfl_xor(zq, 32);
        if (lane == 0) pq_sh[qs] = zq;   // unique writer per compact qs
    }

    // cross-wave reductions
#pragma unroll
    for (int vt = 0; vt < 7; ++vt) {
        if (vt < nvt) {
#pragma unroll
            for (int r = 0; r < 4; ++r) {
                float x = pvacc[vt][r];
                x += __shfl_xor(x, 1); x += __shfl_xor(x, 2);
                x += __shfl_xor(x, 4); x += __shfl_xor(x, 8);
                if (col == 0) atomicAdd(&pv_sh[vt * 16 + rg * 4 + r], x);
            }
        }
    }
    {
        float x = za0;
        x += __shfl_xor(x, 16); x += __shfl_xor(x, 32);
        if (rg == 0) atomicAdd(&pa_sh[col], x);
        float y = za1;
        y += __shfl_xor(y, 16); y += __shfl_xor(y, 32);
        if (rg == 0) atomicAdd(&pa_sh[16 + col], y);
    }
    __syncthreads();

    // fused normalize + scatter
    if (tid < 64) {
        float x = (lane < qcnt) ? pq_sh[lane] : 0.f;
        x += __shfl_xor(x, 1); x += __shfl_xor(x, 2); x += __shfl_xor(x, 4);
        x += __shfl_xor(x, 8); x += __shfl_xor(x, 16); x += __shfl_xor(x, 32);
        if (lane == 0) zsh = x;
    }
    if (tid < NV) pv[bh * NV + tid] = 0.f;
    if (tid < NQ) pq[bh * NQ + tid] = 0.f;
    if (tid < NA) pa[bh * NA + tid] = 0.f;
    __syncthreads();
    const float invZ = 1.0f / zsh;
    if (tid < vcnt) pv[bh * NV + vidx_g[b * NV + tid]] = pv_sh[tid] * invZ;
    if (tid < qcnt) pq[bh * NQ + qidx_g[b * NQ + tid]] = pq_sh[tid] * invZ;
    if (tid < acnt) pa[bh * NA + aidx_g[b * NA + tid]] = pa_sh[tid] * invZ;
}

// ---------------------------------------------------------------------------
extern "C" void kernel_launch(void* const* d_in, const int* in_sizes, int n_in,
                              void* d_out, int out_size, void* d_ws, size_t ws_size,
                              hipStream_t stream)
{
    const float* v     = (const float*)d_in[0];
    const float* q     = (const float*)d_in[1];
    const float* a     = (const float*)d_in[2];
    const int*   vmask = (const int*)d_in[3];
    const int*   qmask = (const int*)d_in[4];
    const int*   amask = (const int*)d_in[5];
    const float* Wv  = (const float*)d_in[6];
    const float* bv  = (const float*)d_in[7];
    const float* Wq  = (const float*)d_in[8];
    const float* bq  = (const float*)d_in[9];
    const float* Wa  = (const float*)d_in[10];
    const float* ba  = (const float*)d_in[11];
    const float* Wvo = (const float*)d_in[12];
    const float* bvo = (const float*)d_in[13];
    const float* Wqo = (const float*)d_in[14];
    const float* bqo = (const float*)d_in[15];
    const float* Wao = (const float*)d_in[16];
    const float* bao = (const float*)d_in[17];
    float* out = (float*)d_out;          // reference output dtype is FLOAT32

    unsigned short* wsu = (unsigned short*)d_ws;
    unsigned short* WtAll = wsu;                    // 6 * 589824
    unsigned short* vpb   = WtAll + 6 * WELEMS;     // up to 2457600 (compact)
    unsigned short* qpb   = vpb + VP_ELEMS;         // up to 786432
    unsigned short* apb   = qpb + QP_ELEMS;         // up to 786432
    float* fbase   = (float*)(apb + AP_ELEMS);
    float* pv      = fbase;                         // 384*100
    float* pq      = pv + NBH * NV;                 // 384*32
    float* pa      = pq + NBH * NQ;                 // 384*32
    int* vidx_g    = (int*)(pa + NBH * NA);         // 32*100
    int* qidx_g    = vidx_g + BB * NV;              // 32*32
    int* aidx_g    = qidx_g + BB * NQ;              // 32*32
    int* vbase_g   = aidx_g + BB * NA;              // 33
    int* qbase_g   = vbase_g + BB + 1;              // 33
    int* abase_g   = qbase_g + BB + 1;              // 33
    int* rv_list   = abase_g + BB + 1;              // 3200
    int* rq_list   = rv_list + BB * NV;             // 1024
    int* ra_list   = rq_list + BB * NQ;             // 1024
    int* tot_g     = ra_list + BB * NA;             // 3

    prep<<<dim3(PREP_BLOCKS), dim3(256), 0, stream>>>(
        Wv, Wq, Wa, Wvo, Wqo, Wao, WtAll,
        vmask, qmask, amask,
        vidx_g, qidx_g, aidx_g, vbase_g, qbase_g, abase_g,
        rv_list, rq_list, ra_list, tot_g, out);

    gemm_mfma<0><<<dim3(492), dim3(256), 0, stream>>>(
        v, q, a,
        WtAll + 0 * WELEMS, WtAll + 1 * WELEMS, WtAll + 2 * WELEMS,
        bv, bq, ba,
        vpb, qpb, apb,
        nullptr, nullptr, nullptr,
        nullptr, nullptr, nullptr,
        rv_list, rq_list, ra_list, tot_g);

    marginal_norm<<<dim3(NBH), dim3(256), 0, stream>>>(
        vpb, qpb, apb, vbase_g, qbase_g, abase_g,
        vidx_g, qidx_g, aidx_g, pv, pq, pa);

    gemm_mfma<1><<<dim3(492), dim3(256), 0, stream>>>(
        vpb, qpb, apb,
        WtAll + 3 * WELEMS, WtAll + 4 * WELEMS, WtAll + 5 * WELEMS,
        bvo, bqo, bao,
        nullptr, nullptr, nullptr,
        out, out + S1, out + S2,
        pv, pq, pa,
        rv_list, rq_list, ra_list, tot_g);
}

// Round 20
// 67.860 us; speedup vs baseline: 1.7156x; 1.2558x over previous
//
#include <hip/hip_runtime.h>
#include <hip/hip_bf16.h>

#define DIM 768
#define NH  12
#define HW  64
#define BB  32
#define NV  100
#define NQ  32
#define NA  32

#define VP_ELEMS (BB * NV * DIM)   // 2457600
#define QP_ELEMS (BB * NQ * DIM)   // 786432
#define AP_ELEMS (BB * NA * DIM)   // 786432
#define S1 (VP_ELEMS)
#define S2 (S1 + QP_ELEMS)
#define STOT (S2 + AP_ELEMS)       // 4030464
#define WELEMS (DIM * DIM)         // 589824
#define NBH (BB * NH)              // 384
#define PREP_BLOCKS (864 + BB)     // 896
#define NROWS (BB * (NV + NQ + NA)) // 5248

typedef __attribute__((ext_vector_type(8))) short     bf16x8;
typedef __attribute__((ext_vector_type(8))) unsigned short u16x8;
typedef __attribute__((ext_vector_type(4))) float     f32x4;

__device__ __forceinline__ float bf16r(float x) {
    return __bfloat162float(__float2bfloat16(x));
}
__device__ __forceinline__ unsigned short f2bu(float x) {
    __hip_bfloat16 h = __float2bfloat16(x);
    return *reinterpret_cast<unsigned short*>(&h);
}
__device__ __forceinline__ float bu2f(unsigned short u) {
    union { unsigned int i; float f; } c;
    c.i = ((unsigned int)u) << 16;
    return c.f;
}

// ---------------------------------------------------------------------------
// PREP (fused, validated r17): every block zeroes a slice of d_out; blocks
// 0..863 convert/transpose one 64x64 weight tile; blocks 864..895 (one per
// b) do mask compaction (counts, prefix bases, ballot index + row lists).
// ---------------------------------------------------------------------------
__global__ __launch_bounds__(256) void prep(
    const float* __restrict__ W0, const float* __restrict__ W1,
    const float* __restrict__ W2, const float* __restrict__ W3,
    const float* __restrict__ W4, const float* __restrict__ W5,
    unsigned short* __restrict__ WtAll,
    const int* __restrict__ vmask, const int* __restrict__ qmask, const int* __restrict__ amask,
    int* __restrict__ vidx_g, int* __restrict__ qidx_g, int* __restrict__ aidx_g,
    int* __restrict__ vbase_g, int* __restrict__ qbase_g, int* __restrict__ abase_g,
    int* __restrict__ rv_list, int* __restrict__ rq_list, int* __restrict__ ra_list,
    int* __restrict__ tot_g,
    float* __restrict__ out)
{
    const int tid = threadIdx.x;

#pragma unroll
    for (int it = 0; it < 5; ++it) {
        const int e4 = blockIdx.x * 256 + tid + it * (PREP_BLOCKS * 256);
        const int i = e4 * 4;
        if (i < STOT) *(float4*)&out[i] = float4{0.f, 0.f, 0.f, 0.f};
    }

    if (blockIdx.x < 864) {
        __shared__ float tile[64][65];
        const int widx = blockIdx.x / 144;
        const int t    = blockIdx.x % 144;
        const int tr = t / 12, tc = t % 12;
        const float* W = (widx == 0) ? W0 : (widx == 1) ? W1 : (widx == 2) ? W2
                       : (widx == 3) ? W3 : (widx == 4) ? W4 : W5;
        unsigned short* Wt = WtAll + (size_t)widx * WELEMS;
        const int c = tid & 63, r4 = tid >> 6;
#pragma unroll
        for (int it = 0; it < 16; ++it) {
            int r = it * 4 + r4;
            tile[r][c] = W[(size_t)(tr * 64 + r) * DIM + tc * 64 + c];
        }
        __syncthreads();
#pragma unroll
        for (int it = 0; it < 16; ++it) {
            int r = it * 4 + r4;
            Wt[(size_t)(tc * 64 + r) * DIM + tr * 64 + c] = f2bu(tile[c][r]);
        }
        return;
    }

    const int b = blockIdx.x - 864;
    __shared__ int cv[BB], cq[BB], ca[BB];
    __shared__ int bs[3];

    if (tid < BB) {
        int s = 0;
        for (int i = 0; i < NV; ++i) s += (vmask[tid * NV + i] == 0);
        cv[tid] = s;
    } else if (tid >= 64 && tid < 64 + BB) {
        const int bb = tid - 64;
        int s = 0;
        for (int i = 0; i < NQ; ++i) s += (qmask[bb * NQ + i] == 0);
        cq[bb] = s;
    } else if (tid >= 128 && tid < 128 + BB) {
        const int bb = tid - 128;
        int s = 0;
        for (int i = 0; i < NA; ++i) s += (amask[bb * NA + i] == 0);
        ca[bb] = s;
    }
    __syncthreads();

    if (tid == 0) {
        int sv = 0, sq = 0, sa = 0;
        for (int j = 0; j < b; ++j) { sv += cv[j]; sq += cq[j]; sa += ca[j]; }
        bs[0] = sv; bs[1] = sq; bs[2] = sa;
        vbase_g[b] = sv; qbase_g[b] = sq; abase_g[b] = sa;
    }
    if (b == 0 && tid == 1) {
        int sv = 0, sq = 0, sa = 0;
        for (int j = 0; j < BB; ++j) { sv += cv[j]; sq += cq[j]; sa += ca[j]; }
        vbase_g[BB] = sv; qbase_g[BB] = sq; abase_g[BB] = sa;
        tot_g[0] = sv; tot_g[1] = sq; tot_g[2] = sa;
    }
    __syncthreads();
    const int basev = bs[0], baseq = bs[1], basea = bs[2];

    const int lane = tid & 63, w = tid >> 6;
    __shared__ int c0sh;
    const bool mv = (tid < NV) && (vmask[b * NV + tid] == 0);
    const unsigned long long bal = __ballot(mv);
    const int pre = __popcll(bal & ((1ull << lane) - 1ull));
    if (w == 0 && lane == 0) c0sh = __popcll(bal);
    __syncthreads();
    const int vbloc = (w == 0) ? 0 : c0sh;
    if (mv) {
        vidx_g[b * NV + vbloc + pre] = tid;
        rv_list[basev + vbloc + pre] = b * NV + tid;
    }
    const bool mq = (w == 0) && (lane < NQ) && (qmask[b * NQ + lane] == 0);
    const unsigned long long balq = __ballot(mq);
    if (mq) {
        const int preq = __popcll(balq & ((1ull << lane) - 1ull));
        qidx_g[b * NQ + preq] = lane;
        rq_list[baseq + preq] = b * NQ + lane;
    }
    const bool ma = (w == 1) && (lane < NA) && (amask[b * NA + lane] == 0);
    const unsigned long long bala = __ballot(ma);
    if (ma) {
        const int prea = __popcll(bala & ((1ull << lane) - 1ull));
        aidx_g[b * NA + prea] = lane;
        ra_list[basea + prea] = b * NA + lane;
    }
}

// ---------------------------------------------------------------------------
// Projection GEMM (r19's validated gemm_mfma<0>): X f32, rows GATHERED via
// rlist -> dense compact Y bf16. 64x128 tile, 4 waves, BK=32.
// ---------------------------------------------------------------------------
__global__ __launch_bounds__(256) void gemm_proj(
    const float* __restrict__ X0, const float* __restrict__ X1, const float* __restrict__ X2,
    const unsigned short* __restrict__ W0, const unsigned short* __restrict__ W1,
    const unsigned short* __restrict__ W2,
    const float* __restrict__ c0, const float* __restrict__ c1, const float* __restrict__ c2,
    unsigned short* __restrict__ Y0, unsigned short* __restrict__ Y1,
    unsigned short* __restrict__ Y2,
    const int* __restrict__ rv_list, const int* __restrict__ rq_list, const int* __restrict__ ra_list,
    const int* __restrict__ tot_g)
{
    __shared__ unsigned short As[64 * 32];
    __shared__ unsigned short Bs[128 * 32];

    const int t = blockIdx.x;
    int set, loc;
    if (t < 300)      { set = 0; loc = t; }
    else if (t < 396) { set = 1; loc = t - 300; }
    else              { set = 2; loc = t - 396; }
    const int tm = loc / 6, tn = loc % 6;
    const int cnt = tot_g[set];
    const int bm = tm * 64, bn = tn * 128;
    if (bm >= cnt) return;

    const float* Xf          = (set == 0) ? X0 : (set == 1) ? X1 : X2;
    const unsigned short* Wt = (set == 0) ? W0 : (set == 1) ? W1 : W2;
    const float* bias        = (set == 0) ? c0 : (set == 1) ? c1 : c2;
    unsigned short* Y        = (set == 0) ? Y0 : (set == 1) ? Y1 : Y2;
    const int* rlist         = (set == 0) ? rv_list : (set == 1) ? rq_list : ra_list;

    const int tid = threadIdx.x, lane = tid & 63, wave = tid >> 6;
    const int col = lane & 15, rg = lane >> 4;

    const int arow = tid >> 2, akc = (tid & 3) << 3;
    const int brow = tid >> 1, bkc = (tid & 1) << 4;
    const int grow = bm + arow;
    const int asrc = (grow < cnt) ? rlist[grow] : 0;

    f32x4 acc[4][2] = {};

    for (int k0 = 0; k0 < DIM; k0 += 32) {
        u16x8 u = {};
        if (grow < cnt) {
            const float4 f0 = *(const float4*)&Xf[(size_t)asrc * DIM + k0 + akc];
            const float4 f1 = *(const float4*)&Xf[(size_t)asrc * DIM + k0 + akc + 4];
            u[0] = f2bu(f0.x); u[1] = f2bu(f0.y); u[2] = f2bu(f0.z); u[3] = f2bu(f0.w);
            u[4] = f2bu(f1.x); u[5] = f2bu(f1.y); u[6] = f2bu(f1.z); u[7] = f2bu(f1.w);
        }
        *(u16x8*)&As[arow * 32 + akc] = u;
        *(u16x8*)&Bs[brow * 32 + bkc] =
            *(const u16x8*)&Wt[(size_t)(bn + brow) * DIM + k0 + bkc];
        *(u16x8*)&Bs[brow * 32 + bkc + 8] =
            *(const u16x8*)&Wt[(size_t)(bn + brow) * DIM + k0 + bkc + 8];
        __syncthreads();

        bf16x8 af[4], bfr[2];
#pragma unroll
        for (int mi = 0; mi < 4; ++mi)
            af[mi] = *(const bf16x8*)&As[(mi * 16 + col) * 32 + rg * 8];
#pragma unroll
        for (int ni = 0; ni < 2; ++ni)
            bfr[ni] = *(const bf16x8*)&Bs[(wave * 32 + ni * 16 + col) * 32 + rg * 8];
#pragma unroll
        for (int mi = 0; mi < 4; ++mi)
#pragma unroll
            for (int ni = 0; ni < 2; ++ni)
                acc[mi][ni] = __builtin_amdgcn_mfma_f32_16x16x32_bf16(
                    af[mi], bfr[ni], acc[mi][ni], 0, 0, 0);
        __syncthreads();
    }

#pragma unroll
    for (int mi = 0; mi < 4; ++mi) {
#pragma unroll
        for (int r = 0; r < 4; ++r) {
            const int m = bm + mi * 16 + rg * 4 + r;
            if (m >= cnt) continue;
#pragma unroll
            for (int ni = 0; ni < 2; ++ni) {
                const int n = bn + wave * 32 + ni * 16 + col;
                Y[(size_t)m * DIM + n] = f2bu(acc[mi][ni][r] + bias[n]);
            }
        }
    }
}

// ---------------------------------------------------------------------------
// FUSED: out-matmul (independent of marginals) + marginal computation.
// Blocks [0,492): ob = P @ Wo + bo, written UNSCALED as bf16 (dense compact).
// Blocks [492,492+NBH): validated marginal_norm role (r19, bit-identical).
// The two roles share no data -> safe in one launch; marginal latency hides
// under the matmul throughput work.
// ---------------------------------------------------------------------------
__global__ __launch_bounds__(256, 2) void outmm_marginal(
    const unsigned short* __restrict__ vpb, const unsigned short* __restrict__ qpb,
    const unsigned short* __restrict__ apb,
    const unsigned short* __restrict__ W3, const unsigned short* __restrict__ W4,
    const unsigned short* __restrict__ W5,
    const float* __restrict__ bvo, const float* __restrict__ bqo, const float* __restrict__ bao,
    unsigned short* __restrict__ ov, unsigned short* __restrict__ oq, unsigned short* __restrict__ oa,
    const int* __restrict__ vbase_g, const int* __restrict__ qbase_g, const int* __restrict__ abase_g,
    const int* __restrict__ vidx_g, const int* __restrict__ qidx_g, const int* __restrict__ aidx_g,
    float* __restrict__ pv, float* __restrict__ pq, float* __restrict__ pa,
    const int* __restrict__ tot_g)
{
    const int tid = threadIdx.x, lane = tid & 63, wave = tid >> 6;
    const int col = lane & 15, rg = lane >> 4;

    if (blockIdx.x < 492) {
        // ---- out-matmul role (gemm structure validated; unscaled bf16 out) ----
        __shared__ unsigned short As[64 * 32];
        __shared__ unsigned short Bs[128 * 32];
        const int t = blockIdx.x;
        int set, loc;
        if (t < 300)      { set = 0; loc = t; }
        else if (t < 396) { set = 1; loc = t - 300; }
        else              { set = 2; loc = t - 396; }
        const int tm = loc / 6, tn = loc % 6;
        const int cnt = tot_g[set];
        const int bm = tm * 64, bn = tn * 128;
        if (bm >= cnt) return;

        const unsigned short* Xb = (set == 0) ? vpb : (set == 1) ? qpb : apb;
        const unsigned short* Wt = (set == 0) ? W3 : (set == 1) ? W4 : W5;
        const float* bias        = (set == 0) ? bvo : (set == 1) ? bqo : bao;
        unsigned short* Y        = (set == 0) ? ov : (set == 1) ? oq : oa;

        const int arow = tid >> 2, akc = (tid & 3) << 3;
        const int brow = tid >> 1, bkc = (tid & 1) << 4;
        const int grow = bm + arow;

        f32x4 acc[4][2] = {};
        for (int k0 = 0; k0 < DIM; k0 += 32) {
            *(u16x8*)&As[arow * 32 + akc] =
                *(const u16x8*)&Xb[(size_t)grow * DIM + k0 + akc];
            *(u16x8*)&Bs[brow * 32 + bkc] =
                *(const u16x8*)&Wt[(size_t)(bn + brow) * DIM + k0 + bkc];
            *(u16x8*)&Bs[brow * 32 + bkc + 8] =
                *(const u16x8*)&Wt[(size_t)(bn + brow) * DIM + k0 + bkc + 8];
            __syncthreads();

            bf16x8 af[4], bfr[2];
#pragma unroll
            for (int mi = 0; mi < 4; ++mi)
                af[mi] = *(const bf16x8*)&As[(mi * 16 + col) * 32 + rg * 8];
#pragma unroll
            for (int ni = 0; ni < 2; ++ni)
                bfr[ni] = *(const bf16x8*)&Bs[(wave * 32 + ni * 16 + col) * 32 + rg * 8];
#pragma unroll
            for (int mi = 0; mi < 4; ++mi)
#pragma unroll
                for (int ni = 0; ni < 2; ++ni)
                    acc[mi][ni] = __builtin_amdgcn_mfma_f32_16x16x32_bf16(
                        af[mi], bfr[ni], acc[mi][ni], 0, 0, 0);
            __syncthreads();
        }

#pragma unroll
        for (int mi = 0; mi < 4; ++mi) {
#pragma unroll
            for (int r = 0; r < 4; ++r) {
                const int m = bm + mi * 16 + rg * 4 + r;
                if (m >= cnt) continue;
#pragma unroll
                for (int ni = 0; ni < 2; ++ni) {
                    const int n = bn + wave * 32 + ni * 16 + col;
                    Y[(size_t)m * DIM + n] = f2bu(acc[mi][ni][r] + bias[n]);
                }
            }
        }
        return;
    }

    // ---- marginal role (r19 marginal_norm, verbatim; bh = blockIdx.x-492) ----
    const int bh = blockIdx.x - 492;
    const int b = bh / NH, h = bh % NH;

    __shared__ unsigned short vhs[112 * 72];
    __shared__ unsigned short qhs[NQ * 72];
    __shared__ unsigned short ahs[NA * 72];
    __shared__ float aoff[NA];
    __shared__ float pv_sh[112], pa_sh[NA], pq_sh[NQ];
    __shared__ float zsh;

    const int vb0 = vbase_g[b], vcnt = vbase_g[b + 1] - vb0;
    const int qb0 = qbase_g[b], qcnt = qbase_g[b + 1] - qb0;
    const int ab0 = abase_g[b], acnt = abase_g[b + 1] - ab0;

    if (tid < 112) pv_sh[tid] = 0.f;
    if (tid < NA)  { aoff[tid] = (tid < acnt) ? 0.f : -200.f; pa_sh[tid] = 0.f; }

    for (int i = tid >> 3; i < vcnt; i += 32) {
        const int c = tid & 7;
        *(u16x8*)&vhs[i * 72 + c * 8] =
            *(const u16x8*)&vpb[(size_t)(vb0 + i) * DIM + h * 64 + c * 8];
    }
    {
        const int pr = vcnt + (tid >> 3);
        if ((tid >> 3) < 16 && pr < 112) {
            const int c = tid & 7;
            u16x8 z = {};
            *(u16x8*)&vhs[pr * 72 + c * 8] = z;
        }
    }
    for (int i = tid >> 3; i < qcnt; i += 32) {
        const int c = tid & 7;
        *(u16x8*)&qhs[i * 72 + c * 8] =
            *(const u16x8*)&qpb[(size_t)(qb0 + i) * DIM + h * 64 + c * 8];
    }
    for (int i = tid >> 3; i < acnt; i += 32) {
        const int c = tid & 7;
        *(u16x8*)&ahs[i * 72 + c * 8] =
            *(const u16x8*)&apb[(size_t)(ab0 + i) * DIM + h * 64 + c * 8];
    }
    {
        const int pr = acnt + (tid >> 3);
        if ((tid >> 3) < 16 && pr < NA) {
            const int c = tid & 7;
            u16x8 z = {};
            *(u16x8*)&ahs[pr * 72 + c * 8] = z;
        }
    }
    __syncthreads();

    const int nvt = (vcnt + 15) >> 4;
    const int nat = (acnt + 15) >> 4;

    float pvacc[7][4] = {};
    float za0 = 0.f, za1 = 0.f;
    const float sc2 = 0.125f * 1.44269504088896f;   // scale * log2(e)

    for (int qs = wave; qs < qcnt; qs += 4) {
        float zq = 0.f;
#pragma unroll
        for (int ah = 0; ah < 2; ++ah) {
            if (ah < nat) {
                const int ai = (ah << 4) + col;
                const u16x8 qv0 = *(const u16x8*)&qhs[qs * 72 + rg * 8];
                const u16x8 qv1 = *(const u16x8*)&qhs[qs * 72 + 32 + rg * 8];
                const u16x8 av0 = *(const u16x8*)&ahs[ai * 72 + rg * 8];
                const u16x8 av1 = *(const u16x8*)&ahs[ai * 72 + 32 + rg * 8];
                bf16x8 bf0, bf1;
#pragma unroll
                for (int j = 0; j < 8; ++j) {
                    bf0[j] = (short)f2bu(bu2f(qv0[j]) * bu2f(av0[j]));
                    bf1[j] = (short)f2bu(bu2f(qv1[j]) * bu2f(av1[j]));
                }
                const float poff = aoff[ai];
                float ts = 0.f;
#pragma unroll
                for (int vt = 0; vt < 7; ++vt) {
                    if (vt < nvt) {
                        const bf16x8 a0 = *(const bf16x8*)&vhs[(vt * 16 + col) * 72 + rg * 8];
                        const bf16x8 a1 = *(const bf16x8*)&vhs[(vt * 16 + col) * 72 + 32 + rg * 8];
                        f32x4 acc = {};
                        acc = __builtin_amdgcn_mfma_f32_16x16x32_bf16(a0, bf0, acc, 0, 0, 0);
                        acc = __builtin_amdgcn_mfma_f32_16x16x32_bf16(a1, bf1, acc, 0, 0, 0);
                        if ((vt + 1) * 16 <= vcnt) {
#pragma unroll
                            for (int r = 0; r < 4; ++r) {
                                const float e = exp2f(fmaf(acc[r], sc2, poff));
                                pvacc[vt][r] += e;
                                ts += e;
                            }
                        } else {
#pragma unroll
                            for (int r = 0; r < 4; ++r) {
                                const float off = (vt * 16 + rg * 4 + r < vcnt) ? poff : -200.f;
                                const float e = exp2f(fmaf(acc[r], sc2, off));
                                pvacc[vt][r] += e;
                                ts += e;
                            }
                        }
                    }
                }
                if (ah) za1 += ts; else za0 += ts;
                zq += ts;
            }
        }
        zq += __shfl_xor(zq, 1);  zq += __shfl_xor(zq, 2);  zq += __shfl_xor(zq, 4);
        zq += __shfl_xor(zq, 8);  zq += __shfl_xor(zq, 16); zq += __shfl_xor(zq, 32);
        if (lane == 0) pq_sh[qs] = zq;
    }

#pragma unroll
    for (int vt = 0; vt < 7; ++vt) {
        if (vt < nvt) {
#pragma unroll
            for (int r = 0; r < 4; ++r) {
                float x = pvacc[vt][r];
                x += __shfl_xor(x, 1); x += __shfl_xor(x, 2);
                x += __shfl_xor(x, 4); x += __shfl_xor(x, 8);
                if (col == 0) atomicAdd(&pv_sh[vt * 16 + rg * 4 + r], x);
            }
        }
    }
    {
        float x = za0;
        x += __shfl_xor(x, 16); x += __shfl_xor(x, 32);
        if (rg == 0) atomicAdd(&pa_sh[col], x);
        float y = za1;
        y += __shfl_xor(y, 16); y += __shfl_xor(y, 32);
        if (rg == 0) atomicAdd(&pa_sh[16 + col], y);
    }
    __syncthreads();

    if (tid < 64) {
        float x = (lane < qcnt) ? pq_sh[lane] : 0.f;
        x += __shfl_xor(x, 1); x += __shfl_xor(x, 2); x += __shfl_xor(x, 4);
        x += __shfl_xor(x, 8); x += __shfl_xor(x, 16); x += __shfl_xor(x, 32);
        if (lane == 0) zsh = x;
    }
    if (tid < NV) pv[bh * NV + tid] = 0.f;
    if (tid < NQ) pq[bh * NQ + tid] = 0.f;
    if (tid < NA) pa[bh * NA + tid] = 0.f;
    __syncthreads();
    const float invZ = 1.0f / zsh;
    if (tid < vcnt) pv[bh * NV + vidx_g[b * NV + tid]] = pv_sh[tid] * invZ;
    if (tid < qcnt) pq[bh * NQ + qidx_g[b * NQ + tid]] = pq_sh[tid] * invZ;
    if (tid < acnt) pa[bh * NA + aidx_g[b * NA + tid]] = pa_sh[tid] * invZ;
}

// ---------------------------------------------------------------------------
// Scale + scatter: out[src][n] = bf16r(ob[m][n] * mg). One block per compact
// row, 192 threads x 4 cols. d_out pre-zeroed for masked rows (prep).
// ---------------------------------------------------------------------------
__global__ __launch_bounds__(192) void scale_out(
    const unsigned short* __restrict__ ov, const unsigned short* __restrict__ oq,
    const unsigned short* __restrict__ oa,
    const float* __restrict__ pv, const float* __restrict__ pq, const float* __restrict__ pa,
    const int* __restrict__ rv_list, const int* __restrict__ rq_list, const int* __restrict__ ra_list,
    const int* __restrict__ tot_g, float* __restrict__ out)
{
    const int t0 = tot_g[0], t1 = tot_g[1], t2 = tot_g[2];
    int m = blockIdx.x;
    const unsigned short* ob; const float* mg; const int* rl; int S; float* os;
    if (m < t0)           { ob = ov; mg = pv; rl = rv_list; S = NV; os = out; }
    else if (m < t0 + t1) { m -= t0; ob = oq; mg = pq; rl = rq_list; S = NQ; os = out + S1; }
    else if (m < t0 + t1 + t2) { m -= t0 + t1; ob = oa; mg = pa; rl = ra_list; S = NA; os = out + S2; }
    else return;

    const int src = rl[m];
    const int bb = src / S, ss = src - bb * S;
    const int n = threadIdx.x * 4;
    const int h = n >> 6;
    const float mgv = mg[(bb * NH + h) * S + ss];
    const ushort4 u = *(const ushort4*)&ob[(size_t)m * DIM + n];
    float4 o;
    o.x = bf16r(bu2f(u.x) * mgv);
    o.y = bf16r(bu2f(u.y) * mgv);
    o.z = bf16r(bu2f(u.z) * mgv);
    o.w = bf16r(bu2f(u.w) * mgv);
    *(float4*)&os[(size_t)src * DIM + n] = o;
}

// ---------------------------------------------------------------------------
extern "C" void kernel_launch(void* const* d_in, const int* in_sizes, int n_in,
                              void* d_out, int out_size, void* d_ws, size_t ws_size,
                              hipStream_t stream)
{
    const float* v     = (const float*)d_in[0];
    const float* q     = (const float*)d_in[1];
    const float* a     = (const float*)d_in[2];
    const int*   vmask = (const int*)d_in[3];
    const int*   qmask = (const int*)d_in[4];
    const int*   amask = (const int*)d_in[5];
    const float* Wv  = (const float*)d_in[6];
    const float* bv  = (const float*)d_in[7];
    const float* Wq  = (const float*)d_in[8];
    const float* bq  = (const float*)d_in[9];
    const float* Wa  = (const float*)d_in[10];
    const float* ba  = (const float*)d_in[11];
    const float* Wvo = (const float*)d_in[12];
    const float* bvo = (const float*)d_in[13];
    const float* Wqo = (const float*)d_in[14];
    const float* bqo = (const float*)d_in[15];
    const float* Wao = (const float*)d_in[16];
    const float* bao = (const float*)d_in[17];
    float* out = (float*)d_out;          // reference output dtype is FLOAT32

    unsigned short* wsu = (unsigned short*)d_ws;
    unsigned short* WtAll = wsu;                    // 6 * 589824
    unsigned short* vpb   = WtAll + 6 * WELEMS;     // compact projections
    unsigned short* qpb   = vpb + VP_ELEMS;
    unsigned short* apb   = qpb + QP_ELEMS;
    unsigned short* ov    = apb + AP_ELEMS;         // unscaled out (bf16)
    unsigned short* oq    = ov + VP_ELEMS;
    unsigned short* oa    = oq + QP_ELEMS;
    float* fbase   = (float*)(oa + AP_ELEMS);
    float* pv      = fbase;                         // 384*100
    float* pq      = pv + NBH * NV;                 // 384*32
    float* pa      = pq + NBH * NQ;                 // 384*32
    int* vidx_g    = (int*)(pa + NBH * NA);         // 32*100
    int* qidx_g    = vidx_g + BB * NV;              // 32*32
    int* aidx_g    = qidx_g + BB * NQ;              // 32*32
    int* vbase_g   = aidx_g + BB * NA;              // 33
    int* qbase_g   = vbase_g + BB + 1;              // 33
    int* abase_g   = qbase_g + BB + 1;              // 33
    int* rv_list   = abase_g + BB + 1;              // 3200
    int* rq_list   = rv_list + BB * NV;             // 1024
    int* ra_list   = rq_list + BB * NQ;             // 1024
    int* tot_g     = ra_list + BB * NA;             // 3

    prep<<<dim3(PREP_BLOCKS), dim3(256), 0, stream>>>(
        Wv, Wq, Wa, Wvo, Wqo, Wao, WtAll,
        vmask, qmask, amask,
        vidx_g, qidx_g, aidx_g, vbase_g, qbase_g, abase_g,
        rv_list, rq_list, ra_list, tot_g, out);

    gemm_proj<<<dim3(492), dim3(256), 0, stream>>>(
        v, q, a,
        WtAll + 0 * WELEMS, WtAll + 1 * WELEMS, WtAll + 2 * WELEMS,
        bv, bq, ba,
        vpb, qpb, apb,
        rv_list, rq_list, ra_list, tot_g);

    outmm_marginal<<<dim3(492 + NBH), dim3(256), 0, stream>>>(
        vpb, qpb, apb,
        WtAll + 3 * WELEMS, WtAll + 4 * WELEMS, WtAll + 5 * WELEMS,
        bvo, bqo, bao,
        ov, oq, oa,
        vbase_g, qbase_g, abase_g,
        vidx_g, qidx_g, aidx_g,
        pv, pq, pa, tot_g);

    scale_out<<<dim3(NROWS), dim3(192), 0, stream>>>(
        ov, oq, oa, pv, pq, pa,
        rv_list, rq_list, ra_list, tot_g, out);
}

// Round 21
// 65.874 us; speedup vs baseline: 1.7673x; 1.0301x over previous
//
#include <hip/hip_runtime.h>
#include <hip/hip_bf16.h>

#define DIM 768
#define NH  12
#define HW  64
#define BB  32
#define NV  100
#define NQ  32
#define NA  32

#define VP_ELEMS (BB * NV * DIM)   // 2457600
#define QP_ELEMS (BB * NQ * DIM)   // 786432
#define AP_ELEMS (BB * NA * DIM)   // 786432
#define S1 (VP_ELEMS)
#define S2 (S1 + QP_ELEMS)
#define STOT (S2 + AP_ELEMS)       // 4030464
#define WELEMS (DIM * DIM)         // 589824
#define NBH (BB * NH)              // 384
#define NROWS (BB * (NV + NQ + NA)) // 5248
#define P2_BLOCKS (492 + 432)      // 924

typedef __attribute__((ext_vector_type(8))) short     bf16x8;
typedef __attribute__((ext_vector_type(8))) unsigned short u16x8;
typedef __attribute__((ext_vector_type(4))) float     f32x4;

__device__ __forceinline__ float bf16r(float x) {
    return __bfloat162float(__float2bfloat16(x));
}
__device__ __forceinline__ unsigned short f2bu(float x) {
    __hip_bfloat16 h = __float2bfloat16(x);
    return *reinterpret_cast<unsigned short*>(&h);
}
__device__ __forceinline__ float bu2f(unsigned short u) {
    union { unsigned int i; float f; } c;
    c.i = ((unsigned int)u) << 16;
    return c.f;
}

// ---------------------------------------------------------------------------
// Weight convert+transpose tile helper (validated r12 structure).
// ---------------------------------------------------------------------------
__device__ __forceinline__ void conv_tile(
    const float* __restrict__ W, unsigned short* __restrict__ Wt, int t, int tid)
{
    __shared__ float tile[64][65];
    const int tr = t / 12, tc = t % 12;
    const int c = tid & 63, r4 = tid >> 6;
#pragma unroll
    for (int it = 0; it < 16; ++it) {
        int r = it * 4 + r4;
        tile[r][c] = W[(size_t)(tr * 64 + r) * DIM + tc * 64 + c];
    }
    __syncthreads();
#pragma unroll
    for (int it = 0; it < 16; ++it) {
        int r = it * 4 + r4;
        Wt[(size_t)(tc * 64 + r) * DIM + tr * 64 + c] = f2bu(tile[c][r]);
    }
}

// ---------------------------------------------------------------------------
// PREP v2: blocks 0..431 convert W0..W2 (needed by gemm_proj); blocks
// 432..463 (one per b) do mask compaction. d_out zeroing and W3..W5 conv
// moved to the gemm_proj launch (they're only needed later).
// ---------------------------------------------------------------------------
__global__ __launch_bounds__(256) void prep(
    const float* __restrict__ W0, const float* __restrict__ W1,
    const float* __restrict__ W2,
    unsigned short* __restrict__ WtAll,
    const int* __restrict__ vmask, const int* __restrict__ qmask, const int* __restrict__ amask,
    int* __restrict__ vidx_g, int* __restrict__ qidx_g, int* __restrict__ aidx_g,
    int* __restrict__ vbase_g, int* __restrict__ qbase_g, int* __restrict__ abase_g,
    int* __restrict__ rv_list, int* __restrict__ rq_list, int* __restrict__ ra_list,
    int* __restrict__ tot_g)
{
    const int tid = threadIdx.x;

    if (blockIdx.x < 432) {
        const int widx = blockIdx.x / 144;
        const float* W = (widx == 0) ? W0 : (widx == 1) ? W1 : W2;
        conv_tile(W, WtAll + (size_t)widx * WELEMS, blockIdx.x % 144, tid);
        return;
    }

    const int b = blockIdx.x - 432;
    __shared__ int cv[BB], cq[BB], ca[BB];
    __shared__ int bs[3];

    if (tid < BB) {
        int s = 0;
        for (int i = 0; i < NV; ++i) s += (vmask[tid * NV + i] == 0);
        cv[tid] = s;
    } else if (tid >= 64 && tid < 64 + BB) {
        const int bb = tid - 64;
        int s = 0;
        for (int i = 0; i < NQ; ++i) s += (qmask[bb * NQ + i] == 0);
        cq[bb] = s;
    } else if (tid >= 128 && tid < 128 + BB) {
        const int bb = tid - 128;
        int s = 0;
        for (int i = 0; i < NA; ++i) s += (amask[bb * NA + i] == 0);
        ca[bb] = s;
    }
    __syncthreads();

    if (tid == 0) {
        int sv = 0, sq = 0, sa = 0;
        for (int j = 0; j < b; ++j) { sv += cv[j]; sq += cq[j]; sa += ca[j]; }
        bs[0] = sv; bs[1] = sq; bs[2] = sa;
        vbase_g[b] = sv; qbase_g[b] = sq; abase_g[b] = sa;
    }
    if (b == 0 && tid == 1) {
        int sv = 0, sq = 0, sa = 0;
        for (int j = 0; j < BB; ++j) { sv += cv[j]; sq += cq[j]; sa += ca[j]; }
        vbase_g[BB] = sv; qbase_g[BB] = sq; abase_g[BB] = sa;
        tot_g[0] = sv; tot_g[1] = sq; tot_g[2] = sa;
    }
    __syncthreads();
    const int basev = bs[0], baseq = bs[1], basea = bs[2];

    const int lane = tid & 63, w = tid >> 6;
    __shared__ int c0sh;
    const bool mv = (tid < NV) && (vmask[b * NV + tid] == 0);
    const unsigned long long bal = __ballot(mv);
    const int pre = __popcll(bal & ((1ull << lane) - 1ull));
    if (w == 0 && lane == 0) c0sh = __popcll(bal);
    __syncthreads();
    const int vbloc = (w == 0) ? 0 : c0sh;
    if (mv) {
        vidx_g[b * NV + vbloc + pre] = tid;
        rv_list[basev + vbloc + pre] = b * NV + tid;
    }
    const bool mq = (w == 0) && (lane < NQ) && (qmask[b * NQ + lane] == 0);
    const unsigned long long balq = __ballot(mq);
    if (mq) {
        const int preq = __popcll(balq & ((1ull << lane) - 1ull));
        qidx_g[b * NQ + preq] = lane;
        rq_list[baseq + preq] = b * NQ + lane;
    }
    const bool ma = (w == 1) && (lane < NA) && (amask[b * NA + lane] == 0);
    const unsigned long long bala = __ballot(ma);
    if (ma) {
        const int prea = __popcll(bala & ((1ull << lane) - 1ull));
        aidx_g[b * NA + prea] = lane;
        ra_list[basea + prea] = b * NA + lane;
    }
}

// ---------------------------------------------------------------------------
// Launch 2 (fused): all blocks zero a slice of d_out; blocks 0..491 run the
// validated projection GEMM (64x128, row-gather via rlist); blocks 492..923
// convert W3..W5 (needed only by launch 3, runs concurrently).
// ---------------------------------------------------------------------------
__global__ __launch_bounds__(256) void gemm_proj(
    const float* __restrict__ X0, const float* __restrict__ X1, const float* __restrict__ X2,
    const float* __restrict__ W3, const float* __restrict__ W4, const float* __restrict__ W5,
    unsigned short* __restrict__ WtAll,
    const float* __restrict__ c0, const float* __restrict__ c1, const float* __restrict__ c2,
    unsigned short* __restrict__ Y0, unsigned short* __restrict__ Y1,
    unsigned short* __restrict__ Y2,
    const int* __restrict__ rv_list, const int* __restrict__ rq_list, const int* __restrict__ ra_list,
    const int* __restrict__ tot_g,
    float* __restrict__ out)
{
    const int tid = threadIdx.x;

    // zero slice of d_out (all blocks; ~17 KB each)
#pragma unroll
    for (int it = 0; it < 5; ++it) {
        const int e4 = blockIdx.x * 256 + tid + it * (P2_BLOCKS * 256);
        const int i = e4 * 4;
        if (i < STOT) *(float4*)&out[i] = float4{0.f, 0.f, 0.f, 0.f};
    }

    if (blockIdx.x >= 492) {
        const int cblk = blockIdx.x - 492;
        const int widx = 3 + cblk / 144;
        const float* W = (widx == 3) ? W3 : (widx == 4) ? W4 : W5;
        conv_tile(W, WtAll + (size_t)widx * WELEMS, cblk % 144, tid);
        return;
    }

    __shared__ unsigned short As[64 * 32];
    __shared__ unsigned short Bs[128 * 32];

    const int t = blockIdx.x;
    int set, loc;
    if (t < 300)      { set = 0; loc = t; }
    else if (t < 396) { set = 1; loc = t - 300; }
    else              { set = 2; loc = t - 396; }
    const int tm = loc / 6, tn = loc % 6;
    const int cnt = tot_g[set];
    const int bm = tm * 64, bn = tn * 128;
    if (bm >= cnt) return;

    const float* Xf          = (set == 0) ? X0 : (set == 1) ? X1 : X2;
    const unsigned short* Wt = WtAll + (size_t)set * WELEMS;
    const float* bias        = (set == 0) ? c0 : (set == 1) ? c1 : c2;
    unsigned short* Y        = (set == 0) ? Y0 : (set == 1) ? Y1 : Y2;
    const int* rlist         = (set == 0) ? rv_list : (set == 1) ? rq_list : ra_list;

    const int lane = tid & 63, wave = tid >> 6;
    const int col = lane & 15, rg = lane >> 4;

    const int arow = tid >> 2, akc = (tid & 3) << 3;
    const int brow = tid >> 1, bkc = (tid & 1) << 4;
    const int grow = bm + arow;
    const int asrc = (grow < cnt) ? rlist[grow] : 0;

    f32x4 acc[4][2] = {};

    for (int k0 = 0; k0 < DIM; k0 += 32) {
        u16x8 u = {};
        if (grow < cnt) {
            const float4 f0 = *(const float4*)&Xf[(size_t)asrc * DIM + k0 + akc];
            const float4 f1 = *(const float4*)&Xf[(size_t)asrc * DIM + k0 + akc + 4];
            u[0] = f2bu(f0.x); u[1] = f2bu(f0.y); u[2] = f2bu(f0.z); u[3] = f2bu(f0.w);
            u[4] = f2bu(f1.x); u[5] = f2bu(f1.y); u[6] = f2bu(f1.z); u[7] = f2bu(f1.w);
        }
        *(u16x8*)&As[arow * 32 + akc] = u;
        *(u16x8*)&Bs[brow * 32 + bkc] =
            *(const u16x8*)&Wt[(size_t)(bn + brow) * DIM + k0 + bkc];
        *(u16x8*)&Bs[brow * 32 + bkc + 8] =
            *(const u16x8*)&Wt[(size_t)(bn + brow) * DIM + k0 + bkc + 8];
        __syncthreads();

        bf16x8 af[4], bfr[2];
#pragma unroll
        for (int mi = 0; mi < 4; ++mi)
            af[mi] = *(const bf16x8*)&As[(mi * 16 + col) * 32 + rg * 8];
#pragma unroll
        for (int ni = 0; ni < 2; ++ni)
            bfr[ni] = *(const bf16x8*)&Bs[(wave * 32 + ni * 16 + col) * 32 + rg * 8];
#pragma unroll
        for (int mi = 0; mi < 4; ++mi)
#pragma unroll
            for (int ni = 0; ni < 2; ++ni)
                acc[mi][ni] = __builtin_amdgcn_mfma_f32_16x16x32_bf16(
                    af[mi], bfr[ni], acc[mi][ni], 0, 0, 0);
        __syncthreads();
    }

#pragma unroll
    for (int mi = 0; mi < 4; ++mi) {
#pragma unroll
        for (int r = 0; r < 4; ++r) {
            const int m = bm + mi * 16 + rg * 4 + r;
            if (m >= cnt) continue;
#pragma unroll
            for (int ni = 0; ni < 2; ++ni) {
                const int n = bn + wave * 32 + ni * 16 + col;
                Y[(size_t)m * DIM + n] = f2bu(acc[mi][ni][r] + bias[n]);
            }
        }
    }
}

// ---------------------------------------------------------------------------
// FUSED: out-matmul + marginal computation (validated r20).
// Blocks [0,492): ob = P @ Wo + bo, UNSCALED bf16 (dense compact).
// Blocks [492,492+NBH): validated marginal role.
// ---------------------------------------------------------------------------
__global__ __launch_bounds__(256, 2) void outmm_marginal(
    const unsigned short* __restrict__ vpb, const unsigned short* __restrict__ qpb,
    const unsigned short* __restrict__ apb,
    const unsigned short* __restrict__ W3, const unsigned short* __restrict__ W4,
    const unsigned short* __restrict__ W5,
    const float* __restrict__ bvo, const float* __restrict__ bqo, const float* __restrict__ bao,
    unsigned short* __restrict__ ov, unsigned short* __restrict__ oq, unsigned short* __restrict__ oa,
    const int* __restrict__ vbase_g, const int* __restrict__ qbase_g, const int* __restrict__ abase_g,
    const int* __restrict__ vidx_g, const int* __restrict__ qidx_g, const int* __restrict__ aidx_g,
    float* __restrict__ pv, float* __restrict__ pq, float* __restrict__ pa,
    const int* __restrict__ tot_g)
{
    const int tid = threadIdx.x, lane = tid & 63, wave = tid >> 6;
    const int col = lane & 15, rg = lane >> 4;

    if (blockIdx.x < 492) {
        __shared__ unsigned short As[64 * 32];
        __shared__ unsigned short Bs[128 * 32];
        const int t = blockIdx.x;
        int set, loc;
        if (t < 300)      { set = 0; loc = t; }
        else if (t < 396) { set = 1; loc = t - 300; }
        else              { set = 2; loc = t - 396; }
        const int tm = loc / 6, tn = loc % 6;
        const int cnt = tot_g[set];
        const int bm = tm * 64, bn = tn * 128;
        if (bm >= cnt) return;

        const unsigned short* Xb = (set == 0) ? vpb : (set == 1) ? qpb : apb;
        const unsigned short* Wt = (set == 0) ? W3 : (set == 1) ? W4 : W5;
        const float* bias        = (set == 0) ? bvo : (set == 1) ? bqo : bao;
        unsigned short* Y        = (set == 0) ? ov : (set == 1) ? oq : oa;

        const int arow = tid >> 2, akc = (tid & 3) << 3;
        const int brow = tid >> 1, bkc = (tid & 1) << 4;
        const int grow = bm + arow;

        f32x4 acc[4][2] = {};
        for (int k0 = 0; k0 < DIM; k0 += 32) {
            *(u16x8*)&As[arow * 32 + akc] =
                *(const u16x8*)&Xb[(size_t)grow * DIM + k0 + akc];
            *(u16x8*)&Bs[brow * 32 + bkc] =
                *(const u16x8*)&Wt[(size_t)(bn + brow) * DIM + k0 + bkc];
            *(u16x8*)&Bs[brow * 32 + bkc + 8] =
                *(const u16x8*)&Wt[(size_t)(bn + brow) * DIM + k0 + bkc + 8];
            __syncthreads();

            bf16x8 af[4], bfr[2];
#pragma unroll
            for (int mi = 0; mi < 4; ++mi)
                af[mi] = *(const bf16x8*)&As[(mi * 16 + col) * 32 + rg * 8];
#pragma unroll
            for (int ni = 0; ni < 2; ++ni)
                bfr[ni] = *(const bf16x8*)&Bs[(wave * 32 + ni * 16 + col) * 32 + rg * 8];
#pragma unroll
            for (int mi = 0; mi < 4; ++mi)
#pragma unroll
                for (int ni = 0; ni < 2; ++ni)
                    acc[mi][ni] = __builtin_amdgcn_mfma_f32_16x16x32_bf16(
                        af[mi], bfr[ni], acc[mi][ni], 0, 0, 0);
            __syncthreads();
        }

#pragma unroll
        for (int mi = 0; mi < 4; ++mi) {
#pragma unroll
            for (int r = 0; r < 4; ++r) {
                const int m = bm + mi * 16 + rg * 4 + r;
                if (m >= cnt) continue;
#pragma unroll
                for (int ni = 0; ni < 2; ++ni) {
                    const int n = bn + wave * 32 + ni * 16 + col;
                    Y[(size_t)m * DIM + n] = f2bu(acc[mi][ni][r] + bias[n]);
                }
            }
        }
        return;
    }

    const int bh = blockIdx.x - 492;
    const int b = bh / NH, h = bh % NH;

    __shared__ unsigned short vhs[112 * 72];
    __shared__ unsigned short qhs[NQ * 72];
    __shared__ unsigned short ahs[NA * 72];
    __shared__ float aoff[NA];
    __shared__ float pv_sh[112], pa_sh[NA], pq_sh[NQ];
    __shared__ float zsh;

    const int vb0 = vbase_g[b], vcnt = vbase_g[b + 1] - vb0;
    const int qb0 = qbase_g[b], qcnt = qbase_g[b + 1] - qb0;
    const int ab0 = abase_g[b], acnt = abase_g[b + 1] - ab0;

    if (tid < 112) pv_sh[tid] = 0.f;
    if (tid < NA)  { aoff[tid] = (tid < acnt) ? 0.f : -200.f; pa_sh[tid] = 0.f; }

    for (int i = tid >> 3; i < vcnt; i += 32) {
        const int c = tid & 7;
        *(u16x8*)&vhs[i * 72 + c * 8] =
            *(const u16x8*)&vpb[(size_t)(vb0 + i) * DIM + h * 64 + c * 8];
    }
    {
        const int pr = vcnt + (tid >> 3);
        if ((tid >> 3) < 16 && pr < 112) {
            const int c = tid & 7;
            u16x8 z = {};
            *(u16x8*)&vhs[pr * 72 + c * 8] = z;
        }
    }
    for (int i = tid >> 3; i < qcnt; i += 32) {
        const int c = tid & 7;
        *(u16x8*)&qhs[i * 72 + c * 8] =
            *(const u16x8*)&qpb[(size_t)(qb0 + i) * DIM + h * 64 + c * 8];
    }
    for (int i = tid >> 3; i < acnt; i += 32) {
        const int c = tid & 7;
        *(u16x8*)&ahs[i * 72 + c * 8] =
            *(const u16x8*)&apb[(size_t)(ab0 + i) * DIM + h * 64 + c * 8];
    }
    {
        const int pr = acnt + (tid >> 3);
        if ((tid >> 3) < 16 && pr < NA) {
            const int c = tid & 7;
            u16x8 z = {};
            *(u16x8*)&ahs[pr * 72 + c * 8] = z;
        }
    }
    __syncthreads();

    const int nvt = (vcnt + 15) >> 4;
    const int nat = (acnt + 15) >> 4;

    float pvacc[7][4] = {};
    float za0 = 0.f, za1 = 0.f;
    const float sc2 = 0.125f * 1.44269504088896f;   // scale * log2(e)

    for (int qs = wave; qs < qcnt; qs += 4) {
        float zq = 0.f;
#pragma unroll
        for (int ah = 0; ah < 2; ++ah) {
            if (ah < nat) {
                const int ai = (ah << 4) + col;
                const u16x8 qv0 = *(const u16x8*)&qhs[qs * 72 + rg * 8];
                const u16x8 qv1 = *(const u16x8*)&qhs[qs * 72 + 32 + rg * 8];
                const u16x8 av0 = *(const u16x8*)&ahs[ai * 72 + rg * 8];
                const u16x8 av1 = *(const u16x8*)&ahs[ai * 72 + 32 + rg * 8];
                bf16x8 bf0, bf1;
#pragma unroll
                for (int j = 0; j < 8; ++j) {
                    bf0[j] = (short)f2bu(bu2f(qv0[j]) * bu2f(av0[j]));
                    bf1[j] = (short)f2bu(bu2f(qv1[j]) * bu2f(av1[j]));
                }
                const float poff = aoff[ai];
                float ts = 0.f;
#pragma unroll
                for (int vt = 0; vt < 7; ++vt) {
                    if (vt < nvt) {
                        const bf16x8 a0 = *(const bf16x8*)&vhs[(vt * 16 + col) * 72 + rg * 8];
                        const bf16x8 a1 = *(const bf16x8*)&vhs[(vt * 16 + col) * 72 + 32 + rg * 8];
                        f32x4 acc = {};
                        acc = __builtin_amdgcn_mfma_f32_16x16x32_bf16(a0, bf0, acc, 0, 0, 0);
                        acc = __builtin_amdgcn_mfma_f32_16x16x32_bf16(a1, bf1, acc, 0, 0, 0);
                        if ((vt + 1) * 16 <= vcnt) {
#pragma unroll
                            for (int r = 0; r < 4; ++r) {
                                const float e = exp2f(fmaf(acc[r], sc2, poff));
                                pvacc[vt][r] += e;
                                ts += e;
                            }
                        } else {
#pragma unroll
                            for (int r = 0; r < 4; ++r) {
                                const float off = (vt * 16 + rg * 4 + r < vcnt) ? poff : -200.f;
                                const float e = exp2f(fmaf(acc[r], sc2, off));
                                pvacc[vt][r] += e;
                                ts += e;
                            }
                        }
                    }
                }
                if (ah) za1 += ts; else za0 += ts;
                zq += ts;
            }
        }
        zq += __shfl_xor(zq, 1);  zq += __shfl_xor(zq, 2);  zq += __shfl_xor(zq, 4);
        zq += __shfl_xor(zq, 8);  zq += __shfl_xor(zq, 16); zq += __shfl_xor(zq, 32);
        if (lane == 0) pq_sh[qs] = zq;
    }

#pragma unroll
    for (int vt = 0; vt < 7; ++vt) {
        if (vt < nvt) {
#pragma unroll
            for (int r = 0; r < 4; ++r) {
                float x = pvacc[vt][r];
                x += __shfl_xor(x, 1); x += __shfl_xor(x, 2);
                x += __shfl_xor(x, 4); x += __shfl_xor(x, 8);
                if (col == 0) atomicAdd(&pv_sh[vt * 16 + rg * 4 + r], x);
            }
        }
    }
    {
        float x = za0;
        x += __shfl_xor(x, 16); x += __shfl_xor(x, 32);
        if (rg == 0) atomicAdd(&pa_sh[col], x);
        float y = za1;
        y += __shfl_xor(y, 16); y += __shfl_xor(y, 32);
        if (rg == 0) atomicAdd(&pa_sh[16 + col], y);
    }
    __syncthreads();

    if (tid < 64) {
        float x = (lane < qcnt) ? pq_sh[lane] : 0.f;
        x += __shfl_xor(x, 1); x += __shfl_xor(x, 2); x += __shfl_xor(x, 4);
        x += __shfl_xor(x, 8); x += __shfl_xor(x, 16); x += __shfl_xor(x, 32);
        if (lane == 0) zsh = x;
    }
    if (tid < NV) pv[bh * NV + tid] = 0.f;
    if (tid < NQ) pq[bh * NQ + tid] = 0.f;
    if (tid < NA) pa[bh * NA + tid] = 0.f;
    __syncthreads();
    const float invZ = 1.0f / zsh;
    if (tid < vcnt) pv[bh * NV + vidx_g[b * NV + tid]] = pv_sh[tid] * invZ;
    if (tid < qcnt) pq[bh * NQ + qidx_g[b * NQ + tid]] = pq_sh[tid] * invZ;
    if (tid < acnt) pa[bh * NA + aidx_g[b * NA + tid]] = pa_sh[tid] * invZ;
}

// ---------------------------------------------------------------------------
// Scale + scatter (validated r20): out[src][n] = bf16r(ob[m][n] * mg).
// ---------------------------------------------------------------------------
__global__ __launch_bounds__(192) void scale_out(
    const unsigned short* __restrict__ ov, const unsigned short* __restrict__ oq,
    const unsigned short* __restrict__ oa,
    const float* __restrict__ pv, const float* __restrict__ pq, const float* __restrict__ pa,
    const int* __restrict__ rv_list, const int* __restrict__ rq_list, const int* __restrict__ ra_list,
    const int* __restrict__ tot_g, float* __restrict__ out)
{
    const int t0 = tot_g[0], t1 = tot_g[1], t2 = tot_g[2];
    int m = blockIdx.x;
    const unsigned short* ob; const float* mg; const int* rl; int S; float* os;
    if (m < t0)           { ob = ov; mg = pv; rl = rv_list; S = NV; os = out; }
    else if (m < t0 + t1) { m -= t0; ob = oq; mg = pq; rl = rq_list; S = NQ; os = out + S1; }
    else if (m < t0 + t1 + t2) { m -= t0 + t1; ob = oa; mg = pa; rl = ra_list; S = NA; os = out + S2; }
    else return;

    const int src = rl[m];
    const int bb = src / S, ss = src - bb * S;
    const int n = threadIdx.x * 4;
    const int h = n >> 6;
    const float mgv = mg[(bb * NH + h) * S + ss];
    const ushort4 u = *(const ushort4*)&ob[(size_t)m * DIM + n];
    float4 o;
    o.x = bf16r(bu2f(u.x) * mgv);
    o.y = bf16r(bu2f(u.y) * mgv);
    o.z = bf16r(bu2f(u.z) * mgv);
    o.w = bf16r(bu2f(u.w) * mgv);
    *(float4*)&os[(size_t)src * DIM + n] = o;
}

// ---------------------------------------------------------------------------
extern "C" void kernel_launch(void* const* d_in, const int* in_sizes, int n_in,
                              void* d_out, int out_size, void* d_ws, size_t ws_size,
                              hipStream_t stream)
{
    const float* v     = (const float*)d_in[0];
    const float* q     = (const float*)d_in[1];
    const float* a     = (const float*)d_in[2];
    const int*   vmask = (const int*)d_in[3];
    const int*   qmask = (const int*)d_in[4];
    const int*   amask = (const int*)d_in[5];
    const float* Wv  = (const float*)d_in[6];
    const float* bv  = (const float*)d_in[7];
    const float* Wq  = (const float*)d_in[8];
    const float* bq  = (const float*)d_in[9];
    const float* Wa  = (const float*)d_in[10];
    const float* ba  = (const float*)d_in[11];
    const float* Wvo = (const float*)d_in[12];
    const float* bvo = (const float*)d_in[13];
    const float* Wqo = (const float*)d_in[14];
    const float* bqo = (const float*)d_in[15];
    const float* Wao = (const float*)d_in[16];
    const float* bao = (const float*)d_in[17];
    float* out = (float*)d_out;          // reference output dtype is FLOAT32

    unsigned short* wsu = (unsigned short*)d_ws;
    unsigned short* WtAll = wsu;                    // 6 * 589824
    unsigned short* vpb   = WtAll + 6 * WELEMS;     // compact projections
    unsigned short* qpb   = vpb + VP_ELEMS;
    unsigned short* apb   = qpb + QP_ELEMS;
    unsigned short* ov    = apb + AP_ELEMS;         // unscaled out (bf16)
    unsigned short* oq    = ov + VP_ELEMS;
    unsigned short* oa    = oq + QP_ELEMS;
    float* fbase   = (float*)(oa + AP_ELEMS);
    float* pv      = fbase;                         // 384*100
    float* pq      = pv + NBH * NV;                 // 384*32
    float* pa      = pq + NBH * NQ;                 // 384*32
    int* vidx_g    = (int*)(pa + NBH * NA);         // 32*100
    int* qidx_g    = vidx_g + BB * NV;              // 32*32
    int* aidx_g    = qidx_g + BB * NQ;              // 32*32
    int* vbase_g   = aidx_g + BB * NA;              // 33
    int* qbase_g   = vbase_g + BB + 1;              // 33
    int* abase_g   = qbase_g + BB + 1;              // 33
    int* rv_list   = abase_g + BB + 1;              // 3200
    int* rq_list   = rv_list + BB * NV;             // 1024
    int* ra_list   = rq_list + BB * NQ;             // 1024
    int* tot_g     = ra_list + BB * NA;             // 3

    prep<<<dim3(432 + BB), dim3(256), 0, stream>>>(
        Wv, Wq, Wa, WtAll,
        vmask, qmask, amask,
        vidx_g, qidx_g, aidx_g, vbase_g, qbase_g, abase_g,
        rv_list, rq_list, ra_list, tot_g);

    gemm_proj<<<dim3(P2_BLOCKS), dim3(256), 0, stream>>>(
        v, q, a,
        Wvo, Wqo, Wao, WtAll,
        bv, bq, ba,
        vpb, qpb, apb,
        rv_list, rq_list, ra_list, tot_g, out);

    outmm_marginal<<<dim3(492 + NBH), dim3(256), 0, stream>>>(
        vpb, qpb, apb,
        WtAll + 3 * WELEMS, WtAll + 4 * WELEMS, WtAll + 5 * WELEMS,
        bvo, bqo, bao,
        ov, oq, oa,
        vbase_g, qbase_g, abase_g,
        vidx_g, qidx_g, aidx_g,
        pv, pq, pa, tot_g);

    scale_out<<<dim3(NROWS), dim3(192), 0, stream>>>(
        ov, oq, oa, pv, pq, pa,
        rv_list, rq_list, ra_list, tot_g, out);
}